// Round 10
// baseline (724.573 us; speedup 1.0000x reference)
//
#include <hip/hip_runtime.h>
#include <math.h>

// ---- problem constants ----
#define BH 32          // B*H
#define NSEQ 4096
#define EDIM 64
#define MDIM 128
#define NHASH 2
#define NBUCK 32
#define BSZC 128
#define BB 4
#define HH 8
#define DD 512
#define NCHUNK 16      // split-k chunks for kv

// ---- workspace layout (bytes) ---- (R7 layout, ~254 MiB — fits ws budget)
static constexpr size_t OFF_SQQ  = 0;
static constexpr size_t SZ_ROWD  = (size_t)BH*NSEQ*8;
static constexpr size_t OFF_SQK  = OFF_SQQ + SZ_ROWD;
static constexpr size_t OFF_QH   = OFF_SQK + SZ_ROWD;
static constexpr size_t SZ_HASH  = (size_t)NHASH*BH*NSEQ*8;
static constexpr size_t OFF_KH   = OFF_QH + SZ_HASH;
static constexpr size_t OFF_MAXQ = OFF_KH + SZ_HASH;          // 32 doubles
static constexpr size_t OFF_MAXK = OFF_MAXQ + 256;
static constexpr size_t OFF_KLS  = OFF_MAXK + 256;            // 32 uint (ordered-float enc)
static constexpr size_t OFF_QPOS = OFF_KLS + 256;
static constexpr size_t SZ_POS   = (size_t)NHASH*BH*NSEQ*4;
static constexpr size_t OFF_KPOS = OFF_QPOS + SZ_POS;
static constexpr size_t OFF_QREV = OFF_KPOS + SZ_POS;
static constexpr size_t OFF_KREV = OFF_QREV + SZ_POS;
static constexpr size_t OFF_QP   = OFF_KREV + SZ_POS;         // bh*N*M f32
static constexpr size_t SZ_PRIME = (size_t)BH*NSEQ*MDIM*4;
static constexpr size_t OFF_KP   = OFF_QP + SZ_PRIME;         // holds RAW lp forever (R13)
static constexpr size_t OFF_QLS  = OFF_KP + SZ_PRIME;         // bh*N f32
static constexpr size_t OFF_KV   = OFF_QLS + (size_t)BH*NSEQ*4;   // bh*M*E f32
static constexpr size_t OFF_KSUM = OFF_KV + (size_t)BH*MDIM*EDIM*4;
static constexpr size_t OFF_O    = OFF_KSUM + (size_t)BH*MDIM*4;  // NH*bh*N*E f32
static constexpr size_t OFF_LSE  = OFF_O + (size_t)NHASH*BH*NSEQ*EDIM*4;
static constexpr size_t OFF_DSUM = OFF_LSE + (size_t)NHASH*BH*NSEQ*4;
static constexpr size_t OFF_OUTN = OFF_DSUM + (size_t)NHASH*BH*NSEQ*4;  // B*N*D f32
static constexpr size_t OFF_PKV  = OFF_OUTN + (size_t)BB*NSEQ*DD*4;     // 32*16*128*64 f32
static constexpr size_t OFF_PKS  = OFF_PKV + (size_t)BH*NCHUNK*MDIM*EDIM*4;  // 32*16*128 f32
// R11: E2LSH projections (4 fp64/pos, 4 MiB) live in PKV until k_hash consumes them.
static constexpr size_t OFF_PROJ = OFF_PKV;
// R12/R13 bf16 mirrors in DEAD regions:
//   KP bf16 (33.5 MB) in OUTN (written by k_cvt, read by k_bucket; OUTN live only from k_combine on).
//   V  bf16 (16.8 MB) in PKV (written by k_cvt AFTER k_kvred drains PKV).
static constexpr size_t OFF_KPB  = OFF_OUTN;
static constexpr size_t OFF_VB   = OFF_PKV;

#define SQRT_TEMP 0.3535533905932738f
#define HALF_LOG_M 2.4260151319598085f
#define LN2F 0.6931471805599453f

typedef __bf16 bf16_t;
typedef bf16_t bf16x8 __attribute__((ext_vector_type(8)));
typedef bf16_t bf16x4 __attribute__((ext_vector_type(4)));
typedef float  f32x16_t __attribute__((ext_vector_type(16)));
#define Z16 {0.f,0.f,0.f,0.f,0.f,0.f,0.f,0.f,0.f,0.f,0.f,0.f,0.f,0.f,0.f,0.f}

__device__ __forceinline__ unsigned encF(float f){
  unsigned u = __float_as_uint(f);
  return (u & 0x80000000u) ? ~u : (u | 0x80000000u);
}
__device__ __forceinline__ float decF(unsigned e){
  return __uint_as_float((e & 0x80000000u) ? (e ^ 0x80000000u) : ~e);
}

// ---------------- init ----------------
__global__ void k_init(char* __restrict__ ws){
  int idx = blockIdx.x*256 + threadIdx.x;
  if (idx < BH){
    ((unsigned long long*)(ws+OFF_MAXQ))[idx] = 0ull;
    ((unsigned long long*)(ws+OFF_MAXK))[idx] = 0ull;
    ((unsigned*)(ws+OFF_KLS))[idx] = encF(-INFINITY);
  }
}

// ---------------- norms + E2LSH projections in ONE pass (R11/R13) ----------------
__global__ __launch_bounds__(256) void k_sumsq(const float* __restrict__ q, const float* __restrict__ k,
                                               const float* __restrict__ alpha, char* __restrict__ ws){
  int p = blockIdx.x*256 + threadIdx.x;
  int bh = p >> 12, t = p & (NSEQ-1);
  int bo = bh >> 3, hh = bh & 7;
  const float* qr = q + ((size_t)bo*NSEQ + t)*DD + hh*EDIM;
  const float* kr = k + ((size_t)bo*NSEQ + t)*DD + hh*EDIM;
  double sq = 0.0, sk = 0.0, a0 = 0.0, a1 = 0.0, c0 = 0.0, c1 = 0.0;
  for (int e4 = 0; e4 < EDIM; e4 += 4){
    float4 qv4 = *(const float4*)(qr + e4);
    float4 kv4 = *(const float4*)(kr + e4);
    float qs[4] = {qv4.x, qv4.y, qv4.z, qv4.w};
    float ks[4] = {kv4.x, kv4.y, kv4.z, kv4.w};
    #pragma unroll
    for (int j = 0; j < 4; j++){
      double a = qs[j], b = ks[j];
      double al0 = alpha[(e4+j)*2+0], al1 = alpha[(e4+j)*2+1];
      sq = fma(a, a, sq);  sk = fma(b, b, sk);
      a0 = fma(a, al0, a0); a1 = fma(a, al1, a1);
      c0 = fma(b, al0, c0); c1 = fma(b, al1, c1);
    }
  }
  ((double*)(ws+OFF_SQQ))[p] = sq;
  ((double*)(ws+OFF_SQK))[p] = sk;
  double* proj = (double*)(ws+OFF_PROJ);
  proj[p]                       = a0;
  proj[(size_t)BH*NSEQ   + p]   = a1;
  proj[(size_t)BH*NSEQ*2 + p]   = c0;
  proj[(size_t)BH*NSEQ*3 + p]   = c1;
  int lane = threadIdx.x & 63, wid = threadIdx.x >> 6;
  double mq = sq, mk = sk;
  for (int o = 32; o; o >>= 1){ mq = fmax(mq, __shfl_xor(mq, o)); mk = fmax(mk, __shfl_xor(mk, o)); }
  __shared__ double smq[4], smk[4];
  if (!lane){ smq[wid] = mq; smk[wid] = mk; }
  __syncthreads();
  if (!threadIdx.x){
    double a = fmax(fmax(smq[0], smq[1]), fmax(smq[2], smq[3]));
    double b = fmax(fmax(smk[0], smk[1]), fmax(smk[2], smk[3]));
    atomicMax((unsigned long long*)(ws+OFF_MAXQ) + bh, (unsigned long long)__double_as_longlong(a));
    atomicMax((unsigned long long*)(ws+OFF_MAXK) + bh, (unsigned long long)__double_as_longlong(b));
  }
}

// ---------------- E2LSH hash finalize (elementwise) ----------------
__global__ __launch_bounds__(256) void k_hash(const float* __restrict__ alpha, const float* __restrict__ beta,
                                              char* __restrict__ ws){
  int p = blockIdx.x*256 + threadIdx.x;
  int bh = p >> 12;
  double mqk = ((const double*)(ws+OFF_MAXQ))[bh] + ((const double*)(ws+OFF_MAXK))[bh];
  double sq  = ((const double*)(ws+OFF_SQQ))[p];
  double sk  = ((const double*)(ws+OFF_SQK))[p];
  double extq = sqrt(fmax(mqk - sq, 0.0));
  double extk = sqrt(fmax(mqk - sk, 0.0));
  const double* proj = (const double*)(ws+OFF_PROJ);
  double a0 = proj[p];
  double a1 = proj[(size_t)BH*NSEQ   + p];
  double c0 = proj[(size_t)BH*NSEQ*2 + p];
  double c1 = proj[(size_t)BH*NSEQ*3 + p];
  a0 += extq * (double)alpha[64*2+0]; a1 += extq * (double)alpha[64*2+1];
  c0 += extk * (double)alpha[65*2+0]; c1 += extk * (double)alpha[65*2+1];
  double b0 = beta[0], b1 = beta[1];
  double* qh = (double*)(ws+OFF_QH);
  double* kh = (double*)(ws+OFF_KH);
  qh[p] = a0 + b0; qh[(size_t)BH*NSEQ + p] = a1 + b1;
  kh[p] = c0 + b0; kh[(size_t)BH*NSEQ + p] = c1 + b1;
}

// ---------------- bitonic argsort — R12 hybrid register/LDS ----------------
__global__ __launch_bounds__(1024) void k_sort(char* __restrict__ ws){
  int row = blockIdx.x;                 // 0..63 q rows, 64..127 k rows
  bool isK = row >= NHASH*BH;
  int r = isK ? row - NHASH*BH : row;
  const double* hash = (const double*)(ws + (isK ? OFF_KH : OFF_QH)) + (size_t)r*NSEQ;
  int* pos = (int*)(ws + (isK ? OFF_KPOS : OFF_QPOS)) + (size_t)r*NSEQ;
  int* rev = (int*)(ws + (isK ? OFF_KREV : OFF_QREV)) + (size_t)r*NSEQ;
  __shared__ double ks_[NSEQ];
  __shared__ int    is_[NSEQ];
  int tid = threadIdx.x, lane = tid & 63;

  double key[4]; int idx[4];
  #pragma unroll
  for (int m = 0; m < 4; m++){ int i = m*1024 + tid; key[m] = hash[i]; idx[m] = i; }

  #pragma unroll
  for (int k = 2; k <= 64; k <<= 1){
    #pragma unroll
    for (int j = 32; j > 0; j >>= 1){
      if (j > (k >> 1)) continue;
      #pragma unroll
      for (int m = 0; m < 4; m++){
        int i = m*1024 + tid;
        bool up = ((i & k) == 0);
        double pk = __shfl_xor(key[m], j);
        int    pi = __shfl_xor(idx[m], j);
        bool isLower = ((lane & j) == 0);
        double lo = isLower ? key[m] : pk;
        double hi = isLower ? pk : key[m];
        if ((lo > hi) == up){ key[m] = pk; idx[m] = pi; }
      }
    }
  }
  #pragma unroll
  for (int m = 0; m < 4; m++){ int i = m*1024 + tid; ks_[i] = key[m]; is_[i] = idx[m]; }
  __syncthreads();

  for (int k = 128; k <= NSEQ; k <<= 1){
    for (int j = k >> 1; j >= 64; j >>= 1){
      for (int i = tid; i < NSEQ; i += 1024){
        int ixj = i ^ j;
        if (ixj > i){
          double a = ks_[i], b = ks_[ixj];
          bool up = ((i & k) == 0);
          if ((a > b) == up){
            ks_[i] = b; ks_[ixj] = a;
            int tmp = is_[i]; is_[i] = is_[ixj]; is_[ixj] = tmp;
          }
        }
      }
      __syncthreads();
    }
    #pragma unroll
    for (int m = 0; m < 4; m++){ int i = m*1024 + tid; key[m] = ks_[i]; idx[m] = is_[i]; }
    #pragma unroll
    for (int j = 32; j > 0; j >>= 1){
      #pragma unroll
      for (int m = 0; m < 4; m++){
        int i = m*1024 + tid;
        bool up = ((i & k) == 0);
        double pk = __shfl_xor(key[m], j);
        int    pi = __shfl_xor(idx[m], j);
        bool isLower = ((lane & j) == 0);
        double lo = isLower ? key[m] : pk;
        double hi = isLower ? pk : key[m];
        if ((lo > hi) == up){ key[m] = pk; idx[m] = pi; }
      }
    }
    #pragma unroll
    for (int m = 0; m < 4; m++){ int i = m*1024 + tid; ks_[i] = key[m]; is_[i] = idx[m]; }
    __syncthreads();
  }
  for (int i = tid; i < NSEQ; i += 1024){ int t = is_[i]; pos[i] = t; rev[t] = i; }
}

// ---------------- R16: Performer features — W pinned in VGPRs via asm, x via ds_read_b128 ----------------
// R15's VGPR=84 proved the compiler rematerializes the W loads inside the loop
// despite __launch_bounds__(256,2). Fix: empty-asm "+v" keep-alive on every W
// component after the load — an opaque def the compiler cannot rematerialize
// past (guide rule #17). x broadcast read as float4 (16 ds_read_b128/position
// instead of 64 ds_read_b32). Same values, same sequential-e fmaf order as
// R13/R15 => bit-identical outputs.
__global__ __launch_bounds__(256, 2) void k_feat(const float* __restrict__ query, const float* __restrict__ key,
                                                 const float* __restrict__ projW, char* __restrict__ ws){
  int tid = threadIdx.x, lane = tid & 63, wid = tid >> 6;
  __shared__ __align__(16) float s_x[4][EDIM];
  float4 w0v[16], w1v[16];          // 128 VGPRs of W, loaded once and PINNED
  #pragma unroll
  for (int e4 = 0; e4 < 16; e4++){
    w0v[e4] = *(const float4*)(projW + (size_t)lane*EDIM + e4*4);
    w1v[e4] = *(const float4*)(projW + (size_t)(64+lane)*EDIM + e4*4);
  }
  #pragma unroll
  for (int e4 = 0; e4 < 16; e4++){
    asm volatile("" : "+v"(w0v[e4].x), "+v"(w0v[e4].y), "+v"(w0v[e4].z), "+v"(w0v[e4].w));
    asm volatile("" : "+v"(w1v[e4].x), "+v"(w1v[e4].y), "+v"(w1v[e4].z), "+v"(w1v[e4].w));
  }
  float* qp  = (float*)(ws+OFF_QP);
  float* qls = (float*)(ws+OFF_QLS);
  float* kp  = (float*)(ws+OFF_KP);
  // ---- q half ----
  for (int it = 0; it < 16; it++){
    int p = blockIdx.x*64 + wid*16 + it;
    int bh = p >> 12, t = p & (NSEQ-1), bo = bh >> 3, hh = bh & 7;
    float xv = query[((size_t)bo*NSEQ + t)*DD + hh*EDIM + lane] * SQRT_TEMP;
    s_x[wid][lane] = xv;
    float ss = xv*xv;
    for (int o = 32; o; o >>= 1) ss += __shfl_xor(ss, o);
    float a0 = 0.f, a1 = 0.f;
    #pragma unroll
    for (int e4 = 0; e4 < 16; e4++){
      float4 sx = *(const float4*)&s_x[wid][e4*4];
      float sxs[4] = {sx.x, sx.y, sx.z, sx.w};
      float w0[4] = {w0v[e4].x, w0v[e4].y, w0v[e4].z, w0v[e4].w};
      float w1[4] = {w1v[e4].x, w1v[e4].y, w1v[e4].z, w1v[e4].w};
      #pragma unroll
      for (int j = 0; j < 4; j++){
        a0 = fmaf(sxs[j], w0[j], a0);
        a1 = fmaf(sxs[j], w1[j], a1);
      }
    }
    float c = 0.5f*ss + HALF_LOG_M;
    float lp0 = a0 - c, lp1 = a1 - c;
    float mx = fmaxf(lp0, lp1);
    for (int o = 32; o; o >>= 1) mx = fmaxf(mx, __shfl_xor(mx, o));
    size_t base = (size_t)p*MDIM;
    qp[base + lane]      = expf(lp0 - mx);
    qp[base + 64 + lane] = expf(lp1 - mx);
    if (!lane) qls[p] = mx;
  }
  // ---- k half ----
  int bh0 = (blockIdx.x*64) >> 12;
  float bmax = -INFINITY;
  for (int it = 0; it < 16; it++){
    int p = blockIdx.x*64 + wid*16 + it;
    int bh = p >> 12, t = p & (NSEQ-1), bo = bh >> 3, hh = bh & 7;
    float xv = key[((size_t)bo*NSEQ + t)*DD + hh*EDIM + lane] * SQRT_TEMP;
    s_x[wid][lane] = xv;
    float ss = xv*xv;
    for (int o = 32; o; o >>= 1) ss += __shfl_xor(ss, o);
    float a0 = 0.f, a1 = 0.f;
    #pragma unroll
    for (int e4 = 0; e4 < 16; e4++){
      float4 sx = *(const float4*)&s_x[wid][e4*4];
      float sxs[4] = {sx.x, sx.y, sx.z, sx.w};
      float w0[4] = {w0v[e4].x, w0v[e4].y, w0v[e4].z, w0v[e4].w};
      float w1[4] = {w1v[e4].x, w1v[e4].y, w1v[e4].z, w1v[e4].w};
      #pragma unroll
      for (int j = 0; j < 4; j++){
        a0 = fmaf(sxs[j], w0[j], a0);
        a1 = fmaf(sxs[j], w1[j], a1);
      }
    }
    float c = 0.5f*ss + HALF_LOG_M;
    float lp0 = a0 - c, lp1 = a1 - c;
    size_t base = (size_t)p*MDIM;
    kp[base + lane]      = lp0;
    kp[base + 64 + lane] = lp1;
    float mx = fmaxf(lp0, lp1);
    for (int o = 32; o; o >>= 1) mx = fmaxf(mx, __shfl_xor(mx, o));
    bmax = fmaxf(bmax, mx);
  }
  __shared__ float wm[4];
  if (!lane) wm[wid] = bmax;
  __syncthreads();
  if (!tid){
    float m = fmaxf(fmaxf(wm[0], wm[1]), fmaxf(wm[2], wm[3]));
    atomicMax((unsigned*)(ws+OFF_KLS) + bh0, encF(m));
  }
}

// ---------------- kv split-k stage 1 — R13: exp applied inline while staging ----------------
__global__ __launch_bounds__(256, 4) void k_kv(const float* __restrict__ value, char* __restrict__ ws){
  int b = blockIdx.x >> 4;          // bh
  int chunk = blockIdx.x & 15;      // 16 chunks x 256 seq positions
  int bo = b >> 3, hh = b & 7;
  const float* kp = (const float*)(ws+OFF_KP) + (size_t)b*NSEQ*MDIM;  // raw lp
  float stab = decF(((const unsigned*)(ws+OFF_KLS))[b]);
  __shared__ float skp[32][MDIM];   // 16 KB
  __shared__ float sv [32][EDIM];   //  8 KB
  int tid = threadIdx.x;
  int d = tid & 63, mg = tid >> 6;
  int m0 = mg*32;
  float acc[32];
  #pragma unroll
  for (int i = 0; i < 32; i++) acc[i] = 0.f;
  float ksacc = 0.f;
  #pragma unroll 1
  for (int s0 = chunk*256; s0 < chunk*256 + 256; s0 += 32){
    __syncthreads();
    {
      const float4* src = (const float4*)(kp + (size_t)s0*MDIM);
      #pragma unroll
      for (int l = tid; l < 32*MDIM/4; l += 256){
        float4 x = src[l];
        x.x = expf(x.x - stab); x.y = expf(x.y - stab);
        x.z = expf(x.z - stab); x.w = expf(x.w - stab);
        ((float4*)skp)[l] = x;
      }
    }
    #pragma unroll
    for (int l = tid; l < 32*EDIM/4; l += 256){
      int r = l >> 4, c4 = (l & 15) << 2;
      *(float4*)&sv[r][c4] = *(const float4*)(value + ((size_t)bo*NSEQ + s0 + r)*DD + hh*EDIM + c4);
    }
    __syncthreads();
    #pragma unroll 1
    for (int ss = 0; ss < 32; ss += 2){
      float vv0 = sv[ss+0][d];
      float vv1 = sv[ss+1][d];
      #pragma unroll
      for (int mq = 0; mq < 8; mq++){
        float4 k0 = *(const float4*)&skp[ss+0][m0 + mq*4];
        float4 k1 = *(const float4*)&skp[ss+1][m0 + mq*4];
        acc[mq*4+0] = fmaf(k0.x, vv0, acc[mq*4+0]);
        acc[mq*4+1] = fmaf(k0.y, vv0, acc[mq*4+1]);
        acc[mq*4+2] = fmaf(k0.z, vv0, acc[mq*4+2]);
        acc[mq*4+3] = fmaf(k0.w, vv0, acc[mq*4+3]);
        acc[mq*4+0] = fmaf(k1.x, vv1, acc[mq*4+0]);
        acc[mq*4+1] = fmaf(k1.y, vv1, acc[mq*4+1]);
        acc[mq*4+2] = fmaf(k1.z, vv1, acc[mq*4+2]);
        acc[mq*4+3] = fmaf(k1.w, vv1, acc[mq*4+3]);
      }
    }
    if (tid < 128){
      #pragma unroll
      for (int ss = 0; ss < 32; ss++) ksacc += skp[ss][tid];
    }
  }
  float* pkv = (float*)(ws+OFF_PKV) + ((size_t)(b*NCHUNK + chunk)*MDIM + m0)*EDIM + d;
  #pragma unroll
  for (int mi = 0; mi < 32; mi++) pkv[mi*EDIM] = acc[mi];
  if (tid < 128)
    ((float*)(ws+OFF_PKS))[(b*NCHUNK + chunk)*MDIM + tid] = ksacc;
}

// ---------------- kv split-k stage 2 ----------------
__global__ __launch_bounds__(256) void k_kvred(char* __restrict__ ws){
  int blk = blockIdx.x;
  if (blk < 1024){                              // kv: 32*128*64 = 262144 elements
    int idx = blk*256 + threadIdx.x;
    int b = idx >> 13, rem = idx & 8191;
    const float* pkv = (const float*)(ws+OFF_PKV);
    float s = 0.f;
    #pragma unroll
    for (int c = 0; c < NCHUNK; c++) s += pkv[(((size_t)b*NCHUNK + c) << 13) + rem];
    ((float*)(ws+OFF_KV))[idx] = s;
  } else {                                      // ksum: 32*128 = 4096 elements
    int j = (blk - 1024)*256 + threadIdx.x;
    const float* pks = (const float*)(ws+OFF_PKS);
    int b = j >> 7, m = j & 127;
    float s = 0.f;
    #pragma unroll
    for (int c = 0; c < NCHUNK; c++) s += pks[(b*NCHUNK + c)*MDIM + m];
    ((float*)(ws+OFF_KSUM))[j] = s;
  }
}

// ---------------- R13: kpb (exp+cast of lp) and vb mirrors in one kernel ----------------
__global__ __launch_bounds__(256) void k_cvt(const float* __restrict__ value, char* __restrict__ ws){
  int blk = blockIdx.x;
  if (blk < 16384){                                   // kp half: 4.19M float4
    size_t idx = (size_t)blk*256 + threadIdx.x;
    const float4* kp = (const float4*)(ws+OFF_KP);    // raw lp
    bf16_t* kpb = (bf16_t*)(ws+OFF_KPB);
    int b = (int)(idx >> 17);
    float stab = decF(((const unsigned*)(ws+OFF_KLS))[b]);
    float4 v = kp[idx];
    v.x = expf(v.x - stab); v.y = expf(v.y - stab);
    v.z = expf(v.z - stab); v.w = expf(v.w - stab);
    *(bf16x4*)(kpb + idx*4) = (bf16x4){(bf16_t)v.x,(bf16_t)v.y,(bf16_t)v.z,(bf16_t)v.w};
  } else {                                            // v half: 2.1M float4
    bf16_t* vb = (bf16_t*)(ws+OFF_VB);
    size_t idx = (size_t)(blk - 16384)*256 + threadIdx.x;
    int e4 = (int)(idx & 15) << 2;
    int t  = (int)((idx >> 4) & 4095);
    int b  = (int)(idx >> 16);
    int bo = b >> 3, hh = b & 7;
    float4 x = *(const float4*)(value + ((size_t)bo*NSEQ + t)*DD + hh*EDIM + e4);
    *(bf16x4*)(vb + ((size_t)b*NSEQ + t)*EDIM + e4) =
        (bf16x4){(bf16_t)x.x,(bf16_t)x.y,(bf16_t)x.z,(bf16_t)x.w};
  }
}

// ---------------- bucketed exact correction — MFMA (R13 version) ----------------
__global__ __launch_bounds__(256, 2) void k_bucket(const float* __restrict__ query,
                                                   const float* __restrict__ key,
                                                   char* __restrict__ ws){
  __shared__ __align__(16) bf16_t s_kT[128*72];    // Kt[j][e],  stride 72  (18.4 KB)
  __shared__ __align__(16) bf16_t s_kp[128*136];   // KPt[j][m], stride 136 (34.8 KB) — reused as dots[i][j]
  __shared__ __align__(16) bf16_t s_v [64*136];    // Vt[d][j],  stride 136 (17.4 KB)
  __shared__ int   s_tq[128], s_tk[128], s_qb[128], s_kb[128];
  __shared__ float s_pls[128];

  int blk = blockIdx.x;
  int h = blk >> 10;           // hash
  int b = (blk >> 5) & 31;     // bh
  int n = blk & 31;            // bucket
  int tid = threadIdx.x, lane = tid & 63, wid = tid >> 6;
  int col = lane & 31, half = lane >> 5;
  int bo = b >> 3, hh = b & 7;

  const int* kpos  = (const int*)(ws+OFF_KPOS) + ((size_t)h*BH + b)*NSEQ + n*BSZC;
  const int* qpos  = (const int*)(ws+OFF_QPOS) + ((size_t)h*BH + b)*NSEQ + n*BSZC;
  const int* qrev0 = (const int*)(ws+OFF_QREV) + (size_t)b*NSEQ;
  const int* qrev1 = (const int*)(ws+OFF_QREV) + ((size_t)BH + b)*NSEQ;
  const int* krev0 = (const int*)(ws+OFF_KREV) + (size_t)b*NSEQ;
  const int* krev1 = (const int*)(ws+OFF_KREV) + ((size_t)BH + b)*NSEQ;
  const float* qp_g = (const float*)(ws+OFF_QP) + (size_t)b*NSEQ*MDIM;
  const bf16_t* kpb_g = (const bf16_t*)(ws+OFF_KPB) + (size_t)b*NSEQ*MDIM;
  const bf16_t* vb_g  = (const bf16_t*)(ws+OFF_VB)  + (size_t)b*NSEQ*EDIM;
  const float* qls  = (const float*)(ws+OFF_QLS) + (size_t)b*NSEQ;
  float klsb = decF(((const unsigned*)(ws+OFF_KLS))[b]);

  if (tid < 128){
    int t = qpos[tid];
    s_tq[tid]  = t;
    s_pls[tid] = qls[t] + klsb;
    s_qb[tid]  = (qrev0[t] >> 7) | ((qrev1[t] >> 7) << 16);
  } else {
    int j = tid - 128;
    int t = kpos[j];
    s_tk[j] = t;
    s_kb[j] = (krev0[t] >> 7) | ((krev1[t] >> 7) << 16);
  }
  __syncthreads();

  // ---- prefetch per-lane A-fragments (raw) — latency hides under staging ----
  int mrow = wid*32 + col;
  int tq_m = s_tq[mrow];
  const float* qr  = query + ((size_t)bo*NSEQ + tq_m)*DD + hh*EDIM + half*8;
  const float* qpr = qp_g + (size_t)tq_m*MDIM + half*8;
  float4 aqf[8];
  #pragma unroll
  for (int kb = 0; kb < 4; kb++){
    aqf[2*kb]   = *(const float4*)(qr + kb*16);
    aqf[2*kb+1] = *(const float4*)(qr + kb*16 + 4);
  }
  float4 aqpf[16];
  #pragma unroll
  for (int kb = 0; kb < 8; kb++){
    aqpf[2*kb]   = *(const float4*)(qpr + kb*16);
    aqpf[2*kb+1] = *(const float4*)(qpr + kb*16 + 4);
  }

  for (int l = tid; l < 128*16; l += 256){            // K: 128 rows x 64 e (f32)
    int j = l >> 4, e4 = (l & 15) << 2;
    int t = s_tk[j];
    float4 x = *(const float4*)(key + ((size_t)bo*NSEQ + t)*DD + hh*EDIM + e4);
    bf16x4 y = {(bf16_t)x.x, (bf16_t)x.y, (bf16_t)x.z, (bf16_t)x.w};
    *(bf16x4*)&s_kT[j*72 + e4] = y;
  }
  for (int l = tid; l < 128*16; l += 256){            // KP: 128 rows x 128 m (bf16x8)
    int j = l >> 4, m8 = (l & 15) << 3;
    int t = s_tk[j];
    *(bf16x8*)&s_kp[j*136 + m8] = *(const bf16x8*)(kpb_g + (size_t)t*MDIM + m8);
  }
  for (int l = tid; l < 128*8; l += 256){             // V (bf16x8) -> Vt[d][j]
    int j = l >> 3, d8 = (l & 7) << 3;
    int t = s_tk[j];
    bf16x8 vv = *(const bf16x8*)(vb_g + (size_t)t*EDIM + d8);
    #pragma unroll
    for (int i = 0; i < 8; i++) s_v[(d8+i)*136 + j] = vv[i];
  }
  __syncthreads();

  float* o_g   = (float*)(ws+OFF_O)    + ((size_t)h*BH + b)*NSEQ*EDIM;
  float* lse_g = (float*)(ws+OFF_LSE)  + ((size_t)h*BH + b)*NSEQ;
  float* dsm_g = (float*)(ws+OFF_DSUM) + ((size_t)h*BH + b)*NSEQ;

  // ---- matmul 1: inner = Q @ K^T ----
  bf16x8 aq[4];
  #pragma unroll
  for (int kb = 0; kb < 4; kb++){
    float4 x0 = aqf[2*kb], x1 = aqf[2*kb+1];
    aq[kb] = (bf16x8){(bf16_t)x0.x,(bf16_t)x0.y,(bf16_t)x0.z,(bf16_t)x0.w,
                      (bf16_t)x1.x,(bf16_t)x1.y,(bf16_t)x1.z,(bf16_t)x1.w};
  }
  f32x16_t ain[4] = {Z16, Z16, Z16, Z16};
  #pragma unroll
  for (int jt = 0; jt < 4; jt++){
    #pragma unroll
    for (int kb = 0; kb < 4; kb++){
      bf16x8 bk = *(const bf16x8*)&s_kT[(jt*32 + col)*72 + kb*16 + half*8];
      ain[jt] = __builtin_amdgcn_mfma_f32_32x32x16_bf16(aq[kb], bk, ain[jt], 0, 0, 0);
    }
  }

  // ---- matmul 2: dots_prime = QP @ KP^T ----
  bf16x8 aqp[8];
  #pragma unroll
  for (int kb = 0; kb < 8; kb++){
    float4 x0 = aqpf[2*kb], x1 = aqpf[2*kb+1];
    aqp[kb] = (bf16x8){(bf16_t)x0.x,(bf16_t)x0.y,(bf16_t)x0.z,(bf16_t)x0.w,
                       (bf16_t)x1.x,(bf16_t)x1.y,(bf16_t)x1.z,(bf16_t)x1.w};
  }
  f32x16_t apr[4] = {Z16, Z16, Z16, Z16};
  #pragma unroll
  for (int jt = 0; jt < 4; jt++){
    #pragma unroll
    for (int kb = 0; kb < 8; kb++){
      bf16x8 bk = *(const bf16x8*)&s_kp[(jt*32 + col)*136 + kb*16 + half*8];
      apr[jt] = __builtin_amdgcn_mfma_f32_32x32x16_bf16(aqp[kb], bk, apr[jt], 0, 0, 0);
    }
  }
  __syncthreads();   // everyone done reading s_kp — safe to overwrite with dots

  // ---- softmax-correction ----
  float pls_r[16]; int qb_r[16];
  #pragma unroll
  for (int i = 0; i < 16; i++){
    int r = wid*32 + (i & 3) + 8*(i >> 2) + 4*half;
    pls_r[i] = s_pls[r];
    qb_r[i]  = s_qb[r];
  }
  float mx[16];
  #pragma unroll
  for (int i = 0; i < 16; i++) mx[i] = -INFINITY;
  #pragma unroll
  for (int jt = 0; jt < 4; jt++){
    int kbp = s_kb[jt*32 + col];
    int kb0 = kbp & 0xffff, kb1 = kbp >> 16;
    #pragma unroll
    for (int i = 0; i < 16; i++){
      int dup2 = ((qb_r[i] & 0xffff) == kb0) & ((qb_r[i] >> 16) == kb1);
      float in = ain[jt][i]*0.125f - (dup2 ? LN2F : 0.0f);
      float dp = dup2 ? apr[jt][i]*0.5f : apr[jt][i];
      ain[jt][i] = in; apr[jt][i] = dp;
      mx[i] = fmaxf(mx[i], in);
    }
  }
  #pragma unroll
  for (int i = 0; i < 16; i++){
    #pragma unroll
    for (int o = 16; o; o >>= 1) mx[i] = fmaxf(mx[i], __shfl_xor(mx[i], o));
  }
  float L[16], eps[16], dsum[16];
  #pragma unroll
  for (int i = 0; i < 16; i++){
    L[i] = fmaxf(mx[i], pls_r[i]);
    eps[i] = expf(pls_r[i] - L[i]);
    dsum[i] = 0.f;
  }
  #pragma unroll
  for (int jt = 0; jt < 4; jt++){
    #pragma unroll
    for (int i = 0; i < 16; i++){
      float d = expf(ain[jt][i] - L[i]) - apr[jt][i]*eps[i];
      dsum[i] += d;
      int r = wid*32 + (i & 3) + 8*(i >> 2) + 4*half;
      s_kp[r*136 + jt*32 + col] = (bf16_t)d;        // dots[i][j] (A-layout for matmul 3)
    }
  }
  #pragma unroll
  for (int i = 0; i < 16; i++){
    #pragma unroll
    for (int o = 16; o; o >>= 1) dsum[i] += __shfl_xor(dsum[i], o);
  }
  __syncthreads();

  // ---- matmul 3: so = dots @ V ----
  f32x16_t ao[2] = {Z16, Z16};
  #pragma unroll
  for (int kb = 0; kb < 8; kb++){
    bf16x8 ad = *(const bf16x8*)&s_kp[mrow*136 + kb*16 + half*8];
    #pragma unroll
    for (int dt = 0; dt < 2; dt++){
      bf16x8 bv = *(const bf16x8*)&s_v[(dt*32 + col)*136 + kb*16 + half*8];
      ao[dt] = __builtin_amdgcn_mfma_f32_32x32x16_bf16(ad, bv, ao[dt], 0, 0, 0);
    }
  }

  // ---- epilogue: scatter to unsorted positions ----
  #pragma unroll
  for (int i = 0; i < 16; i++){
    int r = wid*32 + (i & 3) + 8*(i >> 2) + 4*half;
    int t = s_tq[r];
    o_g[(size_t)t*EDIM + col]      = ao[0][i];
    o_g[(size_t)t*EDIM + 32 + col] = ao[1][i];
    if (col == 0){ lse_g[t] = L[i]; dsm_g[t] = dsum[i]; }
  }
}

// ---------------- combine (R11 version) ----------------
__global__ __launch_bounds__(256) void k_combine(char* __restrict__ ws){
  int b = blockIdx.x >> 6;
  int chunk = blockIdx.x & 63;
  int tid = threadIdx.x, lane = tid & 63, wid = tid >> 6;
  __shared__ float s_kv[MDIM*EDIM];
  __shared__ float s_ks[MDIM];
  __shared__ float s_qp[4][MDIM];
  const float* kv = (const float*)(ws+OFF_KV) + (size_t)b*MDIM*EDIM;
  for (int l = tid; l < MDIM*EDIM; l += 256) s_kv[l] = kv[l];
  if (tid < MDIM) s_ks[tid] = ((const float*)(ws+OFF_KSUM))[b*MDIM + tid];
  __syncthreads();
  const float* qp_g  = (const float*)(ws+OFF_QP) + (size_t)b*NSEQ*MDIM;
  const float* qls   = (const float*)(ws+OFF_QLS) + (size_t)b*NSEQ;
  const float* lse_g = (const float*)(ws+OFF_LSE);
  const float* dsm_g = (const float*)(ws+OFF_DSUM);
  const float* o_g   = (const float*)(ws+OFF_O);
  float* outn = (float*)(ws+OFF_OUTN);
  float klsb = decF(((const unsigned*)(ws+OFF_KLS))[b]);
  int bo = b >> 3, hh = b & 7;
  for (int it = 0; it < 16; it++){
    int t = chunk*64 + wid*16 + it;
    float qp0 = qp_g[(size_t)t*MDIM + lane];
    float qp1 = qp_g[(size_t)t*MDIM + 64 + lane];
    s_qp[wid][lane] = qp0; s_qp[wid][64 + lane] = qp1;
    float qkv = 0.f;
    for (int m = 0; m < 128; m++) qkv = fmaf(s_qp[wid][m], s_kv[m*64 + lane], qkv);
    float qk1 = qp0*s_ks[lane] + qp1*s_ks[64 + lane];
    for (int o = 32; o; o >>= 1) qk1 += __shfl_xor(qk1, o);
    size_t pidx = (size_t)b*NSEQ + t;
    float l0 = lse_g[pidx], l1 = lse_g[(size_t)BH*NSEQ + pidx];
    float mx = fmaxf(l0, l1);
    float nls = mx + logf(expf(l0 - mx) + expf(l1 - mx));
    float p0 = expf(l0 - nls), p1 = expf(l1 - nls);
    float ps = expf(qls[t] + klsb - nls);
    float o0 = o_g[pidx*EDIM + lane];
    float o1 = o_g[((size_t)BH*NSEQ + pidx)*EDIM + lane];
    float ds0 = dsm_g[pidx], ds1 = dsm_g[(size_t)BH*NSEQ + pidx];
    float outv = o0*p0 + o1*p1 + qkv*ps;
    float nrm  = ds0*p0 + ds1*p1 + qk1*ps;
    outn[((size_t)bo*NSEQ + t)*DD + hh*EDIM + lane] = outv / fmaxf(nrm, 1e-6f);
  }
}

// ---------------- final projection (R11 version) ----------------
__global__ __launch_bounds__(256) void k_final(const float* __restrict__ outW, const float* __restrict__ outB,
                                               const char* __restrict__ ws, float* __restrict__ out){
  __shared__ float WT[DD*65];      // [d][e], padded
  __shared__ float s_x[4][DD];
  int tid = threadIdx.x, lane = tid & 63, wid = tid >> 6;
  for (int l = tid; l < EDIM*DD; l += 256){
    int e = l >> 9, d = l & 511;
    WT[d*65 + e] = outW[l];
  }
  __syncthreads();
  const float* outn = (const float*)(ws+OFF_OUTN);
  for (int it = 0; it < 16; it++){
    int p = blockIdx.x*64 + wid*16 + it;
    const float* x = outn + (size_t)p*DD;
    #pragma unroll
    for (int c = 0; c < 8; c++) s_x[wid][c*64 + lane] = x[c*64 + lane];
    float acc = 0.f;
    for (int d = 0; d < DD; d++) acc = fmaf(s_x[wid][d], WT[d*65 + lane], acc);
    out[(size_t)p*EDIM + lane] = acc + outB[lane];
  }
}

extern "C" void kernel_launch(void* const* d_in, const int* in_sizes, int n_in,
                              void* d_out, int out_size, void* d_ws, size_t ws_size,
                              hipStream_t stream) {
  const float* query = (const float*)d_in[0];
  const float* key   = (const float*)d_in[1];
  const float* value = (const float*)d_in[2];
  const float* projW = (const float*)d_in[3];
  const float* alpha = (const float*)d_in[4];
  const float* beta  = (const float*)d_in[5];
  const float* outW  = (const float*)d_in[6];
  const float* outB  = (const float*)d_in[7];
  char* ws = (char*)d_ws;
  float* out = (float*)d_out;

  k_init <<<1,    256, 0, stream>>>(ws);
  k_sumsq<<<512,  256, 0, stream>>>(query, key, alpha, ws);
  k_hash <<<512,  256, 0, stream>>>(alpha, beta, ws);
  k_sort <<<128, 1024, 0, stream>>>(ws);
  k_feat <<<2048, 256, 0, stream>>>(query, key, projW, ws);
  k_kv   <<<512,  256, 0, stream>>>(value, ws);
  k_kvred<<<1040, 256, 0, stream>>>(ws);
  k_cvt  <<<24576,256, 0, stream>>>(value, ws);
  k_bucket<<<2048,256, 0, stream>>>(query, key, ws);
  k_combine<<<2048,256,0, stream>>>(ws);
  k_final<<<256,  256, 0, stream>>>(outW, outB, ws, out);
}

// Round 11
// 684.049 us; speedup vs baseline: 1.0592x; 1.0592x over previous
//
#include <hip/hip_runtime.h>
#include <math.h>

// ---- problem constants ----
#define BH 32          // B*H
#define NSEQ 4096
#define EDIM 64
#define MDIM 128
#define NHASH 2
#define NBUCK 32
#define BSZC 128
#define BB 4
#define HH 8
#define DD 512
#define NCHUNK 16      // split-k chunks for kv

// ---- workspace layout (bytes) ---- (R7 layout, ~254 MiB — fits ws budget)
static constexpr size_t OFF_SQQ  = 0;
static constexpr size_t SZ_ROWD  = (size_t)BH*NSEQ*8;
static constexpr size_t OFF_SQK  = OFF_SQQ + SZ_ROWD;
static constexpr size_t OFF_QH   = OFF_SQK + SZ_ROWD;
static constexpr size_t SZ_HASH  = (size_t)NHASH*BH*NSEQ*8;
static constexpr size_t OFF_KH   = OFF_QH + SZ_HASH;
static constexpr size_t OFF_MAXQ = OFF_KH + SZ_HASH;          // 32 doubles
static constexpr size_t OFF_MAXK = OFF_MAXQ + 256;
static constexpr size_t OFF_KLS  = OFF_MAXK + 256;            // 32 uint (ordered-float enc)
static constexpr size_t OFF_QPOS = OFF_KLS + 256;
static constexpr size_t SZ_POS   = (size_t)NHASH*BH*NSEQ*4;
static constexpr size_t OFF_KPOS = OFF_QPOS + SZ_POS;
static constexpr size_t OFF_QREV = OFF_KPOS + SZ_POS;
static constexpr size_t OFF_KREV = OFF_QREV + SZ_POS;
static constexpr size_t OFF_QP   = OFF_KREV + SZ_POS;         // bh*N*M f32
static constexpr size_t SZ_PRIME = (size_t)BH*NSEQ*MDIM*4;
static constexpr size_t OFF_KP   = OFF_QP + SZ_PRIME;         // holds RAW lp forever (R13)
static constexpr size_t OFF_QLS  = OFF_KP + SZ_PRIME;         // bh*N f32
static constexpr size_t OFF_KV   = OFF_QLS + (size_t)BH*NSEQ*4;   // bh*M*E f32
static constexpr size_t OFF_KSUM = OFF_KV + (size_t)BH*MDIM*EDIM*4;
static constexpr size_t OFF_O    = OFF_KSUM + (size_t)BH*MDIM*4;  // NH*bh*N*E f32
static constexpr size_t OFF_LSE  = OFF_O + (size_t)NHASH*BH*NSEQ*EDIM*4;
static constexpr size_t OFF_DSUM = OFF_LSE + (size_t)NHASH*BH*NSEQ*4;
static constexpr size_t OFF_OUTN = OFF_DSUM + (size_t)NHASH*BH*NSEQ*4;  // B*N*D f32
static constexpr size_t OFF_PKV  = OFF_OUTN + (size_t)BB*NSEQ*DD*4;     // 32*16*128*64 f32
static constexpr size_t OFF_PKS  = OFF_PKV + (size_t)BH*NCHUNK*MDIM*EDIM*4;  // 32*16*128 f32
// R11: E2LSH projections (4 fp64/pos, 4 MiB) live in PKV until k_hash consumes them.
static constexpr size_t OFF_PROJ = OFF_PKV;
// R12/R13 bf16 mirrors in DEAD regions:
//   KP bf16 (33.5 MB) in OUTN (written by k_cvt, read by k_bucket; OUTN live only from k_combine on).
//   V  bf16 (16.8 MB) in PKV (written by k_cvt AFTER k_kvred drains PKV).
static constexpr size_t OFF_KPB  = OFF_OUTN;
static constexpr size_t OFF_VB   = OFF_PKV;

#define SQRT_TEMP 0.3535533905932738f
#define HALF_LOG_M 2.4260151319598085f
#define LN2F 0.6931471805599453f

typedef __bf16 bf16_t;
typedef bf16_t bf16x8 __attribute__((ext_vector_type(8)));
typedef bf16_t bf16x4 __attribute__((ext_vector_type(4)));
typedef float  f32x16_t __attribute__((ext_vector_type(16)));
#define Z16 {0.f,0.f,0.f,0.f,0.f,0.f,0.f,0.f,0.f,0.f,0.f,0.f,0.f,0.f,0.f,0.f}

__device__ __forceinline__ unsigned encF(float f){
  unsigned u = __float_as_uint(f);
  return (u & 0x80000000u) ? ~u : (u | 0x80000000u);
}
__device__ __forceinline__ float decF(unsigned e){
  return __uint_as_float((e & 0x80000000u) ? (e ^ 0x80000000u) : ~e);
}

// ---------------- init ----------------
__global__ void k_init(char* __restrict__ ws){
  int idx = blockIdx.x*256 + threadIdx.x;
  if (idx < BH){
    ((unsigned long long*)(ws+OFF_MAXQ))[idx] = 0ull;
    ((unsigned long long*)(ws+OFF_MAXK))[idx] = 0ull;
    ((unsigned*)(ws+OFF_KLS))[idx] = encF(-INFINITY);
  }
}

// ---------------- norms + E2LSH projections in ONE pass (R11/R13) ----------------
__global__ __launch_bounds__(256) void k_sumsq(const float* __restrict__ q, const float* __restrict__ k,
                                               const float* __restrict__ alpha, char* __restrict__ ws){
  int p = blockIdx.x*256 + threadIdx.x;
  int bh = p >> 12, t = p & (NSEQ-1);
  int bo = bh >> 3, hh = bh & 7;
  const float* qr = q + ((size_t)bo*NSEQ + t)*DD + hh*EDIM;
  const float* kr = k + ((size_t)bo*NSEQ + t)*DD + hh*EDIM;
  double sq = 0.0, sk = 0.0, a0 = 0.0, a1 = 0.0, c0 = 0.0, c1 = 0.0;
  for (int e4 = 0; e4 < EDIM; e4 += 4){
    float4 qv4 = *(const float4*)(qr + e4);
    float4 kv4 = *(const float4*)(kr + e4);
    float qs[4] = {qv4.x, qv4.y, qv4.z, qv4.w};
    float ks[4] = {kv4.x, kv4.y, kv4.z, kv4.w};
    #pragma unroll
    for (int j = 0; j < 4; j++){
      double a = qs[j], b = ks[j];
      double al0 = alpha[(e4+j)*2+0], al1 = alpha[(e4+j)*2+1];
      sq = fma(a, a, sq);  sk = fma(b, b, sk);
      a0 = fma(a, al0, a0); a1 = fma(a, al1, a1);
      c0 = fma(b, al0, c0); c1 = fma(b, al1, c1);
    }
  }
  ((double*)(ws+OFF_SQQ))[p] = sq;
  ((double*)(ws+OFF_SQK))[p] = sk;
  double* proj = (double*)(ws+OFF_PROJ);
  proj[p]                       = a0;
  proj[(size_t)BH*NSEQ   + p]   = a1;
  proj[(size_t)BH*NSEQ*2 + p]   = c0;
  proj[(size_t)BH*NSEQ*3 + p]   = c1;
  int lane = threadIdx.x & 63, wid = threadIdx.x >> 6;
  double mq = sq, mk = sk;
  for (int o = 32; o; o >>= 1){ mq = fmax(mq, __shfl_xor(mq, o)); mk = fmax(mk, __shfl_xor(mk, o)); }
  __shared__ double smq[4], smk[4];
  if (!lane){ smq[wid] = mq; smk[wid] = mk; }
  __syncthreads();
  if (!threadIdx.x){
    double a = fmax(fmax(smq[0], smq[1]), fmax(smq[2], smq[3]));
    double b = fmax(fmax(smk[0], smk[1]), fmax(smk[2], smk[3]));
    atomicMax((unsigned long long*)(ws+OFF_MAXQ) + bh, (unsigned long long)__double_as_longlong(a));
    atomicMax((unsigned long long*)(ws+OFF_MAXK) + bh, (unsigned long long)__double_as_longlong(b));
  }
}

// ---------------- E2LSH hash finalize (elementwise) ----------------
__global__ __launch_bounds__(256) void k_hash(const float* __restrict__ alpha, const float* __restrict__ beta,
                                              char* __restrict__ ws){
  int p = blockIdx.x*256 + threadIdx.x;
  int bh = p >> 12;
  double mqk = ((const double*)(ws+OFF_MAXQ))[bh] + ((const double*)(ws+OFF_MAXK))[bh];
  double sq  = ((const double*)(ws+OFF_SQQ))[p];
  double sk  = ((const double*)(ws+OFF_SQK))[p];
  double extq = sqrt(fmax(mqk - sq, 0.0));
  double extk = sqrt(fmax(mqk - sk, 0.0));
  const double* proj = (const double*)(ws+OFF_PROJ);
  double a0 = proj[p];
  double a1 = proj[(size_t)BH*NSEQ   + p];
  double c0 = proj[(size_t)BH*NSEQ*2 + p];
  double c1 = proj[(size_t)BH*NSEQ*3 + p];
  a0 += extq * (double)alpha[64*2+0]; a1 += extq * (double)alpha[64*2+1];
  c0 += extk * (double)alpha[65*2+0]; c1 += extk * (double)alpha[65*2+1];
  double b0 = beta[0], b1 = beta[1];
  double* qh = (double*)(ws+OFF_QH);
  double* kh = (double*)(ws+OFF_KH);
  qh[p] = a0 + b0; qh[(size_t)BH*NSEQ + p] = a1 + b1;
  kh[p] = c0 + b0; kh[(size_t)BH*NSEQ + p] = c1 + b1;
}

// ---------------- bitonic argsort — R12 hybrid register/LDS ----------------
__global__ __launch_bounds__(1024) void k_sort(char* __restrict__ ws){
  int row = blockIdx.x;                 // 0..63 q rows, 64..127 k rows
  bool isK = row >= NHASH*BH;
  int r = isK ? row - NHASH*BH : row;
  const double* hash = (const double*)(ws + (isK ? OFF_KH : OFF_QH)) + (size_t)r*NSEQ;
  int* pos = (int*)(ws + (isK ? OFF_KPOS : OFF_QPOS)) + (size_t)r*NSEQ;
  int* rev = (int*)(ws + (isK ? OFF_KREV : OFF_QREV)) + (size_t)r*NSEQ;
  __shared__ double ks_[NSEQ];
  __shared__ int    is_[NSEQ];
  int tid = threadIdx.x, lane = tid & 63;

  double key[4]; int idx[4];
  #pragma unroll
  for (int m = 0; m < 4; m++){ int i = m*1024 + tid; key[m] = hash[i]; idx[m] = i; }

  #pragma unroll
  for (int k = 2; k <= 64; k <<= 1){
    #pragma unroll
    for (int j = 32; j > 0; j >>= 1){
      if (j > (k >> 1)) continue;
      #pragma unroll
      for (int m = 0; m < 4; m++){
        int i = m*1024 + tid;
        bool up = ((i & k) == 0);
        double pk = __shfl_xor(key[m], j);
        int    pi = __shfl_xor(idx[m], j);
        bool isLower = ((lane & j) == 0);
        double lo = isLower ? key[m] : pk;
        double hi = isLower ? pk : key[m];
        if ((lo > hi) == up){ key[m] = pk; idx[m] = pi; }
      }
    }
  }
  #pragma unroll
  for (int m = 0; m < 4; m++){ int i = m*1024 + tid; ks_[i] = key[m]; is_[i] = idx[m]; }
  __syncthreads();

  for (int k = 128; k <= NSEQ; k <<= 1){
    for (int j = k >> 1; j >= 64; j >>= 1){
      for (int i = tid; i < NSEQ; i += 1024){
        int ixj = i ^ j;
        if (ixj > i){
          double a = ks_[i], b = ks_[ixj];
          bool up = ((i & k) == 0);
          if ((a > b) == up){
            ks_[i] = b; ks_[ixj] = a;
            int tmp = is_[i]; is_[i] = is_[ixj]; is_[ixj] = tmp;
          }
        }
      }
      __syncthreads();
    }
    #pragma unroll
    for (int m = 0; m < 4; m++){ int i = m*1024 + tid; key[m] = ks_[i]; idx[m] = is_[i]; }
    #pragma unroll
    for (int j = 32; j > 0; j >>= 1){
      #pragma unroll
      for (int m = 0; m < 4; m++){
        int i = m*1024 + tid;
        bool up = ((i & k) == 0);
        double pk = __shfl_xor(key[m], j);
        int    pi = __shfl_xor(idx[m], j);
        bool isLower = ((lane & j) == 0);
        double lo = isLower ? key[m] : pk;
        double hi = isLower ? pk : key[m];
        if ((lo > hi) == up){ key[m] = pk; idx[m] = pi; }
      }
    }
    #pragma unroll
    for (int m = 0; m < 4; m++){ int i = m*1024 + tid; ks_[i] = key[m]; is_[i] = idx[m]; }
    __syncthreads();
  }
  for (int i = tid; i < NSEQ; i += 1024){ int t = is_[i]; pos[i] = t; rev[t] = i; }
}

// ---------------- R17: Performer features — tiled loop-swap ----------------
// R13 analysis: LDS-BW-bound because each lane re-reads ITS 512B of W from
// LDS per position (128 instr x 256B/wave ~ 320 cyc/position = 136 us floor —
// matches R13's 143). R14-16 failed to keep 128 W regs live (allocator).
// Fix: tile 16 positions/wave; loop e4 OUTER (W chunk: 8 regs, global L1-hit),
// positions INNER (acc a0[16],a1[16]). W live set = 8 regs. Per position:
// 2 L1 W-loads + 16 broadcast ds_read_b128 of x. Accumulation order per
// position is still sequential-e (e4 asc, j asc) => bit-identical outputs.
__global__ __launch_bounds__(256) void k_feat(const float* __restrict__ query, const float* __restrict__ key,
                                              const float* __restrict__ projW, char* __restrict__ ws){
  int tid = threadIdx.x, lane = tid & 63, wid = tid >> 6;
  __shared__ __align__(16) float s_x[4][16][EDIM];   // 16 KB
  float* qp  = (float*)(ws+OFF_QP);
  float* qls = (float*)(ws+OFF_QLS);
  float* kp  = (float*)(ws+OFF_KP);
  const float* w0p = projW + (size_t)lane*EDIM;        // W[lane][e]
  const float* w1p = projW + (size_t)(64+lane)*EDIM;   // W[64+lane][e]

  // ================= q half =================
  {
    float ss[16];
    #pragma unroll
    for (int it = 0; it < 16; it++){
      int p = blockIdx.x*64 + wid*16 + it;
      int bh = p >> 12, t = p & (NSEQ-1), bo = bh >> 3, hh = bh & 7;
      float xv = query[((size_t)bo*NSEQ + t)*DD + hh*EDIM + lane] * SQRT_TEMP;
      s_x[wid][it][lane] = xv;
      float s = xv*xv;
      for (int o = 32; o; o >>= 1) s += __shfl_xor(s, o);
      ss[it] = s;
    }
    float a0[16], a1[16];
    #pragma unroll
    for (int it = 0; it < 16; it++){ a0[it] = 0.f; a1[it] = 0.f; }
    #pragma unroll 1
    for (int e4 = 0; e4 < 16; e4++){
      float4 w0 = *(const float4*)(w0p + e4*4);
      float4 w1 = *(const float4*)(w1p + e4*4);
      #pragma unroll
      for (int it = 0; it < 16; it++){
        float4 sx = *(const float4*)&s_x[wid][it][e4*4];
        a0[it] = fmaf(sx.x, w0.x, a0[it]);
        a1[it] = fmaf(sx.x, w1.x, a1[it]);
        a0[it] = fmaf(sx.y, w0.y, a0[it]);
        a1[it] = fmaf(sx.y, w1.y, a1[it]);
        a0[it] = fmaf(sx.z, w0.z, a0[it]);
        a1[it] = fmaf(sx.z, w1.z, a1[it]);
        a0[it] = fmaf(sx.w, w0.w, a0[it]);
        a1[it] = fmaf(sx.w, w1.w, a1[it]);
      }
    }
    #pragma unroll
    for (int it = 0; it < 16; it++){
      int p = blockIdx.x*64 + wid*16 + it;
      float c = 0.5f*ss[it] + HALF_LOG_M;
      float lp0 = a0[it] - c, lp1 = a1[it] - c;
      float mx = fmaxf(lp0, lp1);
      for (int o = 32; o; o >>= 1) mx = fmaxf(mx, __shfl_xor(mx, o));
      size_t base = (size_t)p*MDIM;
      qp[base + lane]      = expf(lp0 - mx);
      qp[base + 64 + lane] = expf(lp1 - mx);
      if (!lane) qls[p] = mx;
    }
  }

  // ================= k half =================
  int bh0 = (blockIdx.x*64) >> 12;
  float bmax = -INFINITY;
  {
    float ss[16];
    #pragma unroll
    for (int it = 0; it < 16; it++){
      int p = blockIdx.x*64 + wid*16 + it;
      int bh = p >> 12, t = p & (NSEQ-1), bo = bh >> 3, hh = bh & 7;
      float xv = key[((size_t)bo*NSEQ + t)*DD + hh*EDIM + lane] * SQRT_TEMP;
      s_x[wid][it][lane] = xv;
      float s = xv*xv;
      for (int o = 32; o; o >>= 1) s += __shfl_xor(s, o);
      ss[it] = s;
    }
    float a0[16], a1[16];
    #pragma unroll
    for (int it = 0; it < 16; it++){ a0[it] = 0.f; a1[it] = 0.f; }
    #pragma unroll 1
    for (int e4 = 0; e4 < 16; e4++){
      float4 w0 = *(const float4*)(w0p + e4*4);
      float4 w1 = *(const float4*)(w1p + e4*4);
      #pragma unroll
      for (int it = 0; it < 16; it++){
        float4 sx = *(const float4*)&s_x[wid][it][e4*4];
        a0[it] = fmaf(sx.x, w0.x, a0[it]);
        a1[it] = fmaf(sx.x, w1.x, a1[it]);
        a0[it] = fmaf(sx.y, w0.y, a0[it]);
        a1[it] = fmaf(sx.y, w1.y, a1[it]);
        a0[it] = fmaf(sx.z, w0.z, a0[it]);
        a1[it] = fmaf(sx.z, w1.z, a1[it]);
        a0[it] = fmaf(sx.w, w0.w, a0[it]);
        a1[it] = fmaf(sx.w, w1.w, a1[it]);
      }
    }
    #pragma unroll
    for (int it = 0; it < 16; it++){
      int p = blockIdx.x*64 + wid*16 + it;
      float c = 0.5f*ss[it] + HALF_LOG_M;
      float lp0 = a0[it] - c, lp1 = a1[it] - c;
      size_t base = (size_t)p*MDIM;
      kp[base + lane]      = lp0;
      kp[base + 64 + lane] = lp1;
      float mx = fmaxf(lp0, lp1);
      for (int o = 32; o; o >>= 1) mx = fmaxf(mx, __shfl_xor(mx, o));
      bmax = fmaxf(bmax, mx);
    }
  }
  __shared__ float wm[4];
  if (!lane) wm[wid] = bmax;
  __syncthreads();
  if (!tid){
    float m = fmaxf(fmaxf(wm[0], wm[1]), fmaxf(wm[2], wm[3]));
    atomicMax((unsigned*)(ws+OFF_KLS) + bh0, encF(m));
  }
}

// ---------------- kv split-k stage 1 — R13: exp applied inline while staging ----------------
__global__ __launch_bounds__(256, 4) void k_kv(const float* __restrict__ value, char* __restrict__ ws){
  int b = blockIdx.x >> 4;          // bh
  int chunk = blockIdx.x & 15;      // 16 chunks x 256 seq positions
  int bo = b >> 3, hh = b & 7;
  const float* kp = (const float*)(ws+OFF_KP) + (size_t)b*NSEQ*MDIM;  // raw lp
  float stab = decF(((const unsigned*)(ws+OFF_KLS))[b]);
  __shared__ float skp[32][MDIM];   // 16 KB
  __shared__ float sv [32][EDIM];   //  8 KB
  int tid = threadIdx.x;
  int d = tid & 63, mg = tid >> 6;
  int m0 = mg*32;
  float acc[32];
  #pragma unroll
  for (int i = 0; i < 32; i++) acc[i] = 0.f;
  float ksacc = 0.f;
  #pragma unroll 1
  for (int s0 = chunk*256; s0 < chunk*256 + 256; s0 += 32){
    __syncthreads();
    {
      const float4* src = (const float4*)(kp + (size_t)s0*MDIM);
      #pragma unroll
      for (int l = tid; l < 32*MDIM/4; l += 256){
        float4 x = src[l];
        x.x = expf(x.x - stab); x.y = expf(x.y - stab);
        x.z = expf(x.z - stab); x.w = expf(x.w - stab);
        ((float4*)skp)[l] = x;
      }
    }
    #pragma unroll
    for (int l = tid; l < 32*EDIM/4; l += 256){
      int r = l >> 4, c4 = (l & 15) << 2;
      *(float4*)&sv[r][c4] = *(const float4*)(value + ((size_t)bo*NSEQ + s0 + r)*DD + hh*EDIM + c4);
    }
    __syncthreads();
    #pragma unroll 1
    for (int ss = 0; ss < 32; ss += 2){
      float vv0 = sv[ss+0][d];
      float vv1 = sv[ss+1][d];
      #pragma unroll
      for (int mq = 0; mq < 8; mq++){
        float4 k0 = *(const float4*)&skp[ss+0][m0 + mq*4];
        float4 k1 = *(const float4*)&skp[ss+1][m0 + mq*4];
        acc[mq*4+0] = fmaf(k0.x, vv0, acc[mq*4+0]);
        acc[mq*4+1] = fmaf(k0.y, vv0, acc[mq*4+1]);
        acc[mq*4+2] = fmaf(k0.z, vv0, acc[mq*4+2]);
        acc[mq*4+3] = fmaf(k0.w, vv0, acc[mq*4+3]);
        acc[mq*4+0] = fmaf(k1.x, vv1, acc[mq*4+0]);
        acc[mq*4+1] = fmaf(k1.y, vv1, acc[mq*4+1]);
        acc[mq*4+2] = fmaf(k1.z, vv1, acc[mq*4+2]);
        acc[mq*4+3] = fmaf(k1.w, vv1, acc[mq*4+3]);
      }
    }
    if (tid < 128){
      #pragma unroll
      for (int ss = 0; ss < 32; ss++) ksacc += skp[ss][tid];
    }
  }
  float* pkv = (float*)(ws+OFF_PKV) + ((size_t)(b*NCHUNK + chunk)*MDIM + m0)*EDIM + d;
  #pragma unroll
  for (int mi = 0; mi < 32; mi++) pkv[mi*EDIM] = acc[mi];
  if (tid < 128)
    ((float*)(ws+OFF_PKS))[(b*NCHUNK + chunk)*MDIM + tid] = ksacc;
}

// ---------------- kv split-k stage 2 ----------------
__global__ __launch_bounds__(256) void k_kvred(char* __restrict__ ws){
  int blk = blockIdx.x;
  if (blk < 1024){                              // kv: 32*128*64 = 262144 elements
    int idx = blk*256 + threadIdx.x;
    int b = idx >> 13, rem = idx & 8191;
    const float* pkv = (const float*)(ws+OFF_PKV);
    float s = 0.f;
    #pragma unroll
    for (int c = 0; c < NCHUNK; c++) s += pkv[(((size_t)b*NCHUNK + c) << 13) + rem];
    ((float*)(ws+OFF_KV))[idx] = s;
  } else {                                      // ksum: 32*128 = 4096 elements
    int j = (blk - 1024)*256 + threadIdx.x;
    const float* pks = (const float*)(ws+OFF_PKS);
    int b = j >> 7, m = j & 127;
    float s = 0.f;
    #pragma unroll
    for (int c = 0; c < NCHUNK; c++) s += pks[(b*NCHUNK + c)*MDIM + m];
    ((float*)(ws+OFF_KSUM))[j] = s;
  }
}

// ---------------- R13: kpb (exp+cast of lp) and vb mirrors in one kernel ----------------
__global__ __launch_bounds__(256) void k_cvt(const float* __restrict__ value, char* __restrict__ ws){
  int blk = blockIdx.x;
  if (blk < 16384){                                   // kp half: 4.19M float4
    size_t idx = (size_t)blk*256 + threadIdx.x;
    const float4* kp = (const float4*)(ws+OFF_KP);    // raw lp
    bf16_t* kpb = (bf16_t*)(ws+OFF_KPB);
    int b = (int)(idx >> 17);
    float stab = decF(((const unsigned*)(ws+OFF_KLS))[b]);
    float4 v = kp[idx];
    v.x = expf(v.x - stab); v.y = expf(v.y - stab);
    v.z = expf(v.z - stab); v.w = expf(v.w - stab);
    *(bf16x4*)(kpb + idx*4) = (bf16x4){(bf16_t)v.x,(bf16_t)v.y,(bf16_t)v.z,(bf16_t)v.w};
  } else {                                            // v half: 2.1M float4
    bf16_t* vb = (bf16_t*)(ws+OFF_VB);
    size_t idx = (size_t)(blk - 16384)*256 + threadIdx.x;
    int e4 = (int)(idx & 15) << 2;
    int t  = (int)((idx >> 4) & 4095);
    int b  = (int)(idx >> 16);
    int bo = b >> 3, hh = b & 7;
    float4 x = *(const float4*)(value + ((size_t)bo*NSEQ + t)*DD + hh*EDIM + e4);
    *(bf16x4*)(vb + ((size_t)b*NSEQ + t)*EDIM + e4) =
        (bf16x4){(bf16_t)x.x,(bf16_t)x.y,(bf16_t)x.z,(bf16_t)x.w};
  }
}

// ---------------- bucketed exact correction — MFMA (R13 version) ----------------
__global__ __launch_bounds__(256, 2) void k_bucket(const float* __restrict__ query,
                                                   const float* __restrict__ key,
                                                   char* __restrict__ ws){
  __shared__ __align__(16) bf16_t s_kT[128*72];    // Kt[j][e],  stride 72  (18.4 KB)
  __shared__ __align__(16) bf16_t s_kp[128*136];   // KPt[j][m], stride 136 (34.8 KB) — reused as dots[i][j]
  __shared__ __align__(16) bf16_t s_v [64*136];    // Vt[d][j],  stride 136 (17.4 KB)
  __shared__ int   s_tq[128], s_tk[128], s_qb[128], s_kb[128];
  __shared__ float s_pls[128];

  int blk = blockIdx.x;
  int h = blk >> 10;           // hash
  int b = (blk >> 5) & 31;     // bh
  int n = blk & 31;            // bucket
  int tid = threadIdx.x, lane = tid & 63, wid = tid >> 6;
  int col = lane & 31, half = lane >> 5;
  int bo = b >> 3, hh = b & 7;

  const int* kpos  = (const int*)(ws+OFF_KPOS) + ((size_t)h*BH + b)*NSEQ + n*BSZC;
  const int* qpos  = (const int*)(ws+OFF_QPOS) + ((size_t)h*BH + b)*NSEQ + n*BSZC;
  const int* qrev0 = (const int*)(ws+OFF_QREV) + (size_t)b*NSEQ;
  const int* qrev1 = (const int*)(ws+OFF_QREV) + ((size_t)BH + b)*NSEQ;
  const int* krev0 = (const int*)(ws+OFF_KREV) + (size_t)b*NSEQ;
  const int* krev1 = (const int*)(ws+OFF_KREV) + ((size_t)BH + b)*NSEQ;
  const float* qp_g = (const float*)(ws+OFF_QP) + (size_t)b*NSEQ*MDIM;
  const bf16_t* kpb_g = (const bf16_t*)(ws+OFF_KPB) + (size_t)b*NSEQ*MDIM;
  const bf16_t* vb_g  = (const bf16_t*)(ws+OFF_VB)  + (size_t)b*NSEQ*EDIM;
  const float* qls  = (const float*)(ws+OFF_QLS) + (size_t)b*NSEQ;
  float klsb = decF(((const unsigned*)(ws+OFF_KLS))[b]);

  if (tid < 128){
    int t = qpos[tid];
    s_tq[tid]  = t;
    s_pls[tid] = qls[t] + klsb;
    s_qb[tid]  = (qrev0[t] >> 7) | ((qrev1[t] >> 7) << 16);
  } else {
    int j = tid - 128;
    int t = kpos[j];
    s_tk[j] = t;
    s_kb[j] = (krev0[t] >> 7) | ((krev1[t] >> 7) << 16);
  }
  __syncthreads();

  // ---- prefetch per-lane A-fragments (raw) — latency hides under staging ----
  int mrow = wid*32 + col;
  int tq_m = s_tq[mrow];
  const float* qr  = query + ((size_t)bo*NSEQ + tq_m)*DD + hh*EDIM + half*8;
  const float* qpr = qp_g + (size_t)tq_m*MDIM + half*8;
  float4 aqf[8];
  #pragma unroll
  for (int kb = 0; kb < 4; kb++){
    aqf[2*kb]   = *(const float4*)(qr + kb*16);
    aqf[2*kb+1] = *(const float4*)(qr + kb*16 + 4);
  }
  float4 aqpf[16];
  #pragma unroll
  for (int kb = 0; kb < 8; kb++){
    aqpf[2*kb]   = *(const float4*)(qpr + kb*16);
    aqpf[2*kb+1] = *(const float4*)(qpr + kb*16 + 4);
  }

  for (int l = tid; l < 128*16; l += 256){            // K: 128 rows x 64 e (f32)
    int j = l >> 4, e4 = (l & 15) << 2;
    int t = s_tk[j];
    float4 x = *(const float4*)(key + ((size_t)bo*NSEQ + t)*DD + hh*EDIM + e4);
    bf16x4 y = {(bf16_t)x.x, (bf16_t)x.y, (bf16_t)x.z, (bf16_t)x.w};
    *(bf16x4*)&s_kT[j*72 + e4] = y;
  }
  for (int l = tid; l < 128*16; l += 256){            // KP: 128 rows x 128 m (bf16x8)
    int j = l >> 4, m8 = (l & 15) << 3;
    int t = s_tk[j];
    *(bf16x8*)&s_kp[j*136 + m8] = *(const bf16x8*)(kpb_g + (size_t)t*MDIM + m8);
  }
  for (int l = tid; l < 128*8; l += 256){             // V (bf16x8) -> Vt[d][j]
    int j = l >> 3, d8 = (l & 7) << 3;
    int t = s_tk[j];
    bf16x8 vv = *(const bf16x8*)(vb_g + (size_t)t*EDIM + d8);
    #pragma unroll
    for (int i = 0; i < 8; i++) s_v[(d8+i)*136 + j] = vv[i];
  }
  __syncthreads();

  float* o_g   = (float*)(ws+OFF_O)    + ((size_t)h*BH + b)*NSEQ*EDIM;
  float* lse_g = (float*)(ws+OFF_LSE)  + ((size_t)h*BH + b)*NSEQ;
  float* dsm_g = (float*)(ws+OFF_DSUM) + ((size_t)h*BH + b)*NSEQ;

  // ---- matmul 1: inner = Q @ K^T ----
  bf16x8 aq[4];
  #pragma unroll
  for (int kb = 0; kb < 4; kb++){
    float4 x0 = aqf[2*kb], x1 = aqf[2*kb+1];
    aq[kb] = (bf16x8){(bf16_t)x0.x,(bf16_t)x0.y,(bf16_t)x0.z,(bf16_t)x0.w,
                      (bf16_t)x1.x,(bf16_t)x1.y,(bf16_t)x1.z,(bf16_t)x1.w};
  }
  f32x16_t ain[4] = {Z16, Z16, Z16, Z16};
  #pragma unroll
  for (int jt = 0; jt < 4; jt++){
    #pragma unroll
    for (int kb = 0; kb < 4; kb++){
      bf16x8 bk = *(const bf16x8*)&s_kT[(jt*32 + col)*72 + kb*16 + half*8];
      ain[jt] = __builtin_amdgcn_mfma_f32_32x32x16_bf16(aq[kb], bk, ain[jt], 0, 0, 0);
    }
  }

  // ---- matmul 2: dots_prime = QP @ KP^T ----
  bf16x8 aqp[8];
  #pragma unroll
  for (int kb = 0; kb < 8; kb++){
    float4 x0 = aqpf[2*kb], x1 = aqpf[2*kb+1];
    aqp[kb] = (bf16x8){(bf16_t)x0.x,(bf16_t)x0.y,(bf16_t)x0.z,(bf16_t)x0.w,
                       (bf16_t)x1.x,(bf16_t)x1.y,(bf16_t)x1.z,(bf16_t)x1.w};
  }
  f32x16_t apr[4] = {Z16, Z16, Z16, Z16};
  #pragma unroll
  for (int jt = 0; jt < 4; jt++){
    #pragma unroll
    for (int kb = 0; kb < 8; kb++){
      bf16x8 bk = *(const bf16x8*)&s_kp[(jt*32 + col)*136 + kb*16 + half*8];
      apr[jt] = __builtin_amdgcn_mfma_f32_32x32x16_bf16(aqp[kb], bk, apr[jt], 0, 0, 0);
    }
  }
  __syncthreads();   // everyone done reading s_kp — safe to overwrite with dots

  // ---- softmax-correction ----
  float pls_r[16]; int qb_r[16];
  #pragma unroll
  for (int i = 0; i < 16; i++){
    int r = wid*32 + (i & 3) + 8*(i >> 2) + 4*half;
    pls_r[i] = s_pls[r];
    qb_r[i]  = s_qb[r];
  }
  float mx[16];
  #pragma unroll
  for (int i = 0; i < 16; i++) mx[i] = -INFINITY;
  #pragma unroll
  for (int jt = 0; jt < 4; jt++){
    int kbp = s_kb[jt*32 + col];
    int kb0 = kbp & 0xffff, kb1 = kbp >> 16;
    #pragma unroll
    for (int i = 0; i < 16; i++){
      int dup2 = ((qb_r[i] & 0xffff) == kb0) & ((qb_r[i] >> 16) == kb1);
      float in = ain[jt][i]*0.125f - (dup2 ? LN2F : 0.0f);
      float dp = dup2 ? apr[jt][i]*0.5f : apr[jt][i];
      ain[jt][i] = in; apr[jt][i] = dp;
      mx[i] = fmaxf(mx[i], in);
    }
  }
  #pragma unroll
  for (int i = 0; i < 16; i++){
    #pragma unroll
    for (int o = 16; o; o >>= 1) mx[i] = fmaxf(mx[i], __shfl_xor(mx[i], o));
  }
  float L[16], eps[16], dsum[16];
  #pragma unroll
  for (int i = 0; i < 16; i++){
    L[i] = fmaxf(mx[i], pls_r[i]);
    eps[i] = expf(pls_r[i] - L[i]);
    dsum[i] = 0.f;
  }
  #pragma unroll
  for (int jt = 0; jt < 4; jt++){
    #pragma unroll
    for (int i = 0; i < 16; i++){
      float d = expf(ain[jt][i] - L[i]) - apr[jt][i]*eps[i];
      dsum[i] += d;
      int r = wid*32 + (i & 3) + 8*(i >> 2) + 4*half;
      s_kp[r*136 + jt*32 + col] = (bf16_t)d;        // dots[i][j] (A-layout for matmul 3)
    }
  }
  #pragma unroll
  for (int i = 0; i < 16; i++){
    #pragma unroll
    for (int o = 16; o; o >>= 1) dsum[i] += __shfl_xor(dsum[i], o);
  }
  __syncthreads();

  // ---- matmul 3: so = dots @ V ----
  f32x16_t ao[2] = {Z16, Z16};
  #pragma unroll
  for (int kb = 0; kb < 8; kb++){
    bf16x8 ad = *(const bf16x8*)&s_kp[mrow*136 + kb*16 + half*8];
    #pragma unroll
    for (int dt = 0; dt < 2; dt++){
      bf16x8 bv = *(const bf16x8*)&s_v[(dt*32 + col)*136 + kb*16 + half*8];
      ao[dt] = __builtin_amdgcn_mfma_f32_32x32x16_bf16(ad, bv, ao[dt], 0, 0, 0);
    }
  }

  // ---- epilogue: scatter to unsorted positions ----
  #pragma unroll
  for (int i = 0; i < 16; i++){
    int r = wid*32 + (i & 3) + 8*(i >> 2) + 4*half;
    int t = s_tq[r];
    o_g[(size_t)t*EDIM + col]      = ao[0][i];
    o_g[(size_t)t*EDIM + 32 + col] = ao[1][i];
    if (col == 0){ lse_g[t] = L[i]; dsm_g[t] = dsum[i]; }
  }
}

// ---------------- combine (R11 version) ----------------
__global__ __launch_bounds__(256) void k_combine(char* __restrict__ ws){
  int b = blockIdx.x >> 6;
  int chunk = blockIdx.x & 63;
  int tid = threadIdx.x, lane = tid & 63, wid = tid >> 6;
  __shared__ float s_kv[MDIM*EDIM];
  __shared__ float s_ks[MDIM];
  __shared__ float s_qp[4][MDIM];
  const float* kv = (const float*)(ws+OFF_KV) + (size_t)b*MDIM*EDIM;
  for (int l = tid; l < MDIM*EDIM; l += 256) s_kv[l] = kv[l];
  if (tid < MDIM) s_ks[tid] = ((const float*)(ws+OFF_KSUM))[b*MDIM + tid];
  __syncthreads();
  const float* qp_g  = (const float*)(ws+OFF_QP) + (size_t)b*NSEQ*MDIM;
  const float* qls   = (const float*)(ws+OFF_QLS) + (size_t)b*NSEQ;
  const float* lse_g = (const float*)(ws+OFF_LSE);
  const float* dsm_g = (const float*)(ws+OFF_DSUM);
  const float* o_g   = (const float*)(ws+OFF_O);
  float* outn = (float*)(ws+OFF_OUTN);
  float klsb = decF(((const unsigned*)(ws+OFF_KLS))[b]);
  int bo = b >> 3, hh = b & 7;
  for (int it = 0; it < 16; it++){
    int t = chunk*64 + wid*16 + it;
    float qp0 = qp_g[(size_t)t*MDIM + lane];
    float qp1 = qp_g[(size_t)t*MDIM + 64 + lane];
    s_qp[wid][lane] = qp0; s_qp[wid][64 + lane] = qp1;
    float qkv = 0.f;
    for (int m = 0; m < 128; m++) qkv = fmaf(s_qp[wid][m], s_kv[m*64 + lane], qkv);
    float qk1 = qp0*s_ks[lane] + qp1*s_ks[64 + lane];
    for (int o = 32; o; o >>= 1) qk1 += __shfl_xor(qk1, o);
    size_t pidx = (size_t)b*NSEQ + t;
    float l0 = lse_g[pidx], l1 = lse_g[(size_t)BH*NSEQ + pidx];
    float mx = fmaxf(l0, l1);
    float nls = mx + logf(expf(l0 - mx) + expf(l1 - mx));
    float p0 = expf(l0 - nls), p1 = expf(l1 - nls);
    float ps = expf(qls[t] + klsb - nls);
    float o0 = o_g[pidx*EDIM + lane];
    float o1 = o_g[((size_t)BH*NSEQ + pidx)*EDIM + lane];
    float ds0 = dsm_g[pidx], ds1 = dsm_g[(size_t)BH*NSEQ + pidx];
    float outv = o0*p0 + o1*p1 + qkv*ps;
    float nrm  = ds0*p0 + ds1*p1 + qk1*ps;
    outn[((size_t)bo*NSEQ + t)*DD + hh*EDIM + lane] = outv / fmaxf(nrm, 1e-6f);
  }
}

// ---------------- final projection (R11 version) ----------------
__global__ __launch_bounds__(256) void k_final(const float* __restrict__ outW, const float* __restrict__ outB,
                                               const char* __restrict__ ws, float* __restrict__ out){
  __shared__ float WT[DD*65];      // [d][e], padded
  __shared__ float s_x[4][DD];
  int tid = threadIdx.x, lane = tid & 63, wid = tid >> 6;
  for (int l = tid; l < EDIM*DD; l += 256){
    int e = l >> 9, d = l & 511;
    WT[d*65 + e] = outW[l];
  }
  __syncthreads();
  const float* outn = (const float*)(ws+OFF_OUTN);
  for (int it = 0; it < 16; it++){
    int p = blockIdx.x*64 + wid*16 + it;
    const float* x = outn + (size_t)p*DD;
    #pragma unroll
    for (int c = 0; c < 8; c++) s_x[wid][c*64 + lane] = x[c*64 + lane];
    float acc = 0.f;
    for (int d = 0; d < DD; d++) acc = fmaf(s_x[wid][d], WT[d*65 + lane], acc);
    out[(size_t)p*EDIM + lane] = acc + outB[lane];
  }
}

extern "C" void kernel_launch(void* const* d_in, const int* in_sizes, int n_in,
                              void* d_out, int out_size, void* d_ws, size_t ws_size,
                              hipStream_t stream) {
  const float* query = (const float*)d_in[0];
  const float* key   = (const float*)d_in[1];
  const float* value = (const float*)d_in[2];
  const float* projW = (const float*)d_in[3];
  const float* alpha = (const float*)d_in[4];
  const float* beta  = (const float*)d_in[5];
  const float* outW  = (const float*)d_in[6];
  const float* outB  = (const float*)d_in[7];
  char* ws = (char*)d_ws;
  float* out = (float*)d_out;

  k_init <<<1,    256, 0, stream>>>(ws);
  k_sumsq<<<512,  256, 0, stream>>>(query, key, alpha, ws);
  k_hash <<<512,  256, 0, stream>>>(alpha, beta, ws);
  k_sort <<<128, 1024, 0, stream>>>(ws);
  k_feat <<<2048, 256, 0, stream>>>(query, key, projW, ws);
  k_kv   <<<512,  256, 0, stream>>>(value, ws);
  k_kvred<<<1040, 256, 0, stream>>>(ws);
  k_cvt  <<<24576,256, 0, stream>>>(value, ws);
  k_bucket<<<2048,256, 0, stream>>>(query, key, ws);
  k_combine<<<2048,256,0, stream>>>(ws);
  k_final<<<256,  256, 0, stream>>>(outW, outB, ws, out);
}

// Round 12
// 665.168 us; speedup vs baseline: 1.0893x; 1.0284x over previous
//
#include <hip/hip_runtime.h>
#include <math.h>

// ---- problem constants ----
#define BH 32          // B*H
#define NSEQ 4096
#define EDIM 64
#define MDIM 128
#define NHASH 2
#define NBUCK 32
#define BSZC 128
#define BB 4
#define HH 8
#define DD 512
#define NCHUNK 16      // split-k chunks for kv

// ---- workspace layout (bytes) ---- (R7 layout, ~254 MiB — fits ws budget)
static constexpr size_t OFF_SQQ  = 0;
static constexpr size_t SZ_ROWD  = (size_t)BH*NSEQ*8;
static constexpr size_t OFF_SQK  = OFF_SQQ + SZ_ROWD;
static constexpr size_t OFF_QH   = OFF_SQK + SZ_ROWD;
static constexpr size_t SZ_HASH  = (size_t)NHASH*BH*NSEQ*8;
static constexpr size_t OFF_KH   = OFF_QH + SZ_HASH;
static constexpr size_t OFF_MAXQ = OFF_KH + SZ_HASH;          // 32 doubles
static constexpr size_t OFF_MAXK = OFF_MAXQ + 256;
static constexpr size_t OFF_KLS  = OFF_MAXK + 256;            // 32 uint (ordered-float enc)
static constexpr size_t OFF_QPOS = OFF_KLS + 256;
static constexpr size_t SZ_POS   = (size_t)NHASH*BH*NSEQ*4;
static constexpr size_t OFF_KPOS = OFF_QPOS + SZ_POS;
static constexpr size_t OFF_QREV = OFF_KPOS + SZ_POS;
static constexpr size_t OFF_KREV = OFF_QREV + SZ_POS;
static constexpr size_t OFF_QP   = OFF_KREV + SZ_POS;         // bh*N*M f32
static constexpr size_t SZ_PRIME = (size_t)BH*NSEQ*MDIM*4;
static constexpr size_t OFF_KP   = OFF_QP + SZ_PRIME;         // holds RAW lp forever (R13)
static constexpr size_t OFF_QLS  = OFF_KP + SZ_PRIME;         // bh*N f32
static constexpr size_t OFF_KV   = OFF_QLS + (size_t)BH*NSEQ*4;   // bh*M*E f32
static constexpr size_t OFF_KSUM = OFF_KV + (size_t)BH*MDIM*EDIM*4;
static constexpr size_t OFF_O    = OFF_KSUM + (size_t)BH*MDIM*4;  // NH*bh*N*E f32
static constexpr size_t OFF_LSE  = OFF_O + (size_t)NHASH*BH*NSEQ*EDIM*4;
static constexpr size_t OFF_DSUM = OFF_LSE + (size_t)NHASH*BH*NSEQ*4;
static constexpr size_t OFF_OUTN = OFF_DSUM + (size_t)NHASH*BH*NSEQ*4;  // B*N*D f32
static constexpr size_t OFF_PKV  = OFF_OUTN + (size_t)BB*NSEQ*DD*4;     // 32*16*128*64 f32
static constexpr size_t OFF_PKS  = OFF_PKV + (size_t)BH*NCHUNK*MDIM*EDIM*4;  // 32*16*128 f32
// R11: E2LSH projections (4 fp64/pos, 4 MiB) live in PKV until k_hash consumes them.
static constexpr size_t OFF_PROJ = OFF_PKV;
// R12/R13/R18 bf16 mirrors in DEAD regions:
//   KP bf16 (33.5 MB) in OUTN — R18: written by k_kv during staging (same expf+cast).
//   V  bf16 (16.8 MB) in PKV — written by k_cvt AFTER k_kvred drains PKV.
static constexpr size_t OFF_KPB  = OFF_OUTN;
static constexpr size_t OFF_VB   = OFF_PKV;

#define SQRT_TEMP 0.3535533905932738f
#define HALF_LOG_M 2.4260151319598085f
#define LN2F 0.6931471805599453f

typedef __bf16 bf16_t;
typedef bf16_t bf16x8 __attribute__((ext_vector_type(8)));
typedef bf16_t bf16x4 __attribute__((ext_vector_type(4)));
typedef float  f32x16_t __attribute__((ext_vector_type(16)));
#define Z16 {0.f,0.f,0.f,0.f,0.f,0.f,0.f,0.f,0.f,0.f,0.f,0.f,0.f,0.f,0.f,0.f}

__device__ __forceinline__ unsigned encF(float f){
  unsigned u = __float_as_uint(f);
  return (u & 0x80000000u) ? ~u : (u | 0x80000000u);
}
__device__ __forceinline__ float decF(unsigned e){
  return __uint_as_float((e & 0x80000000u) ? (e ^ 0x80000000u) : ~e);
}

// ---------------- init ----------------
__global__ void k_init(char* __restrict__ ws){
  int idx = blockIdx.x*256 + threadIdx.x;
  if (idx < BH){
    ((unsigned long long*)(ws+OFF_MAXQ))[idx] = 0ull;
    ((unsigned long long*)(ws+OFF_MAXK))[idx] = 0ull;
    ((unsigned*)(ws+OFF_KLS))[idx] = encF(-INFINITY);
  }
}

// ---------------- norms + E2LSH projections in ONE pass (R11/R13) ----------------
__global__ __launch_bounds__(256) void k_sumsq(const float* __restrict__ q, const float* __restrict__ k,
                                               const float* __restrict__ alpha, char* __restrict__ ws){
  int p = blockIdx.x*256 + threadIdx.x;
  int bh = p >> 12, t = p & (NSEQ-1);
  int bo = bh >> 3, hh = bh & 7;
  const float* qr = q + ((size_t)bo*NSEQ + t)*DD + hh*EDIM;
  const float* kr = k + ((size_t)bo*NSEQ + t)*DD + hh*EDIM;
  double sq = 0.0, sk = 0.0, a0 = 0.0, a1 = 0.0, c0 = 0.0, c1 = 0.0;
  for (int e4 = 0; e4 < EDIM; e4 += 4){
    float4 qv4 = *(const float4*)(qr + e4);
    float4 kv4 = *(const float4*)(kr + e4);
    float qs[4] = {qv4.x, qv4.y, qv4.z, qv4.w};
    float ks[4] = {kv4.x, kv4.y, kv4.z, kv4.w};
    #pragma unroll
    for (int j = 0; j < 4; j++){
      double a = qs[j], b = ks[j];
      double al0 = alpha[(e4+j)*2+0], al1 = alpha[(e4+j)*2+1];
      sq = fma(a, a, sq);  sk = fma(b, b, sk);
      a0 = fma(a, al0, a0); a1 = fma(a, al1, a1);
      c0 = fma(b, al0, c0); c1 = fma(b, al1, c1);
    }
  }
  ((double*)(ws+OFF_SQQ))[p] = sq;
  ((double*)(ws+OFF_SQK))[p] = sk;
  double* proj = (double*)(ws+OFF_PROJ);
  proj[p]                       = a0;
  proj[(size_t)BH*NSEQ   + p]   = a1;
  proj[(size_t)BH*NSEQ*2 + p]   = c0;
  proj[(size_t)BH*NSEQ*3 + p]   = c1;
  int lane = threadIdx.x & 63, wid = threadIdx.x >> 6;
  double mq = sq, mk = sk;
  for (int o = 32; o; o >>= 1){ mq = fmax(mq, __shfl_xor(mq, o)); mk = fmax(mk, __shfl_xor(mk, o)); }
  __shared__ double smq[4], smk[4];
  if (!lane){ smq[wid] = mq; smk[wid] = mk; }
  __syncthreads();
  if (!threadIdx.x){
    double a = fmax(fmax(smq[0], smq[1]), fmax(smq[2], smq[3]));
    double b = fmax(fmax(smk[0], smk[1]), fmax(smk[2], smk[3]));
    atomicMax((unsigned long long*)(ws+OFF_MAXQ) + bh, (unsigned long long)__double_as_longlong(a));
    atomicMax((unsigned long long*)(ws+OFF_MAXK) + bh, (unsigned long long)__double_as_longlong(b));
  }
}

// ---------------- E2LSH hash finalize (elementwise) ----------------
__global__ __launch_bounds__(256) void k_hash(const float* __restrict__ alpha, const float* __restrict__ beta,
                                              char* __restrict__ ws){
  int p = blockIdx.x*256 + threadIdx.x;
  int bh = p >> 12;
  double mqk = ((const double*)(ws+OFF_MAXQ))[bh] + ((const double*)(ws+OFF_MAXK))[bh];
  double sq  = ((const double*)(ws+OFF_SQQ))[p];
  double sk  = ((const double*)(ws+OFF_SQK))[p];
  double extq = sqrt(fmax(mqk - sq, 0.0));
  double extk = sqrt(fmax(mqk - sk, 0.0));
  const double* proj = (const double*)(ws+OFF_PROJ);
  double a0 = proj[p];
  double a1 = proj[(size_t)BH*NSEQ   + p];
  double c0 = proj[(size_t)BH*NSEQ*2 + p];
  double c1 = proj[(size_t)BH*NSEQ*3 + p];
  a0 += extq * (double)alpha[64*2+0]; a1 += extq * (double)alpha[64*2+1];
  c0 += extk * (double)alpha[65*2+0]; c1 += extk * (double)alpha[65*2+1];
  double b0 = beta[0], b1 = beta[1];
  double* qh = (double*)(ws+OFF_QH);
  double* kh = (double*)(ws+OFF_KH);
  qh[p] = a0 + b0; qh[(size_t)BH*NSEQ + p] = a1 + b1;
  kh[p] = c0 + b0; kh[(size_t)BH*NSEQ + p] = c1 + b1;
}

// ---------------- bitonic argsort — R12 hybrid register/LDS ----------------
__global__ __launch_bounds__(1024) void k_sort(char* __restrict__ ws){
  int row = blockIdx.x;                 // 0..63 q rows, 64..127 k rows
  bool isK = row >= NHASH*BH;
  int r = isK ? row - NHASH*BH : row;
  const double* hash = (const double*)(ws + (isK ? OFF_KH : OFF_QH)) + (size_t)r*NSEQ;
  int* pos = (int*)(ws + (isK ? OFF_KPOS : OFF_QPOS)) + (size_t)r*NSEQ;
  int* rev = (int*)(ws + (isK ? OFF_KREV : OFF_QREV)) + (size_t)r*NSEQ;
  __shared__ double ks_[NSEQ];
  __shared__ int    is_[NSEQ];
  int tid = threadIdx.x, lane = tid & 63;

  double key[4]; int idx[4];
  #pragma unroll
  for (int m = 0; m < 4; m++){ int i = m*1024 + tid; key[m] = hash[i]; idx[m] = i; }

  #pragma unroll
  for (int k = 2; k <= 64; k <<= 1){
    #pragma unroll
    for (int j = 32; j > 0; j >>= 1){
      if (j > (k >> 1)) continue;
      #pragma unroll
      for (int m = 0; m < 4; m++){
        int i = m*1024 + tid;
        bool up = ((i & k) == 0);
        double pk = __shfl_xor(key[m], j);
        int    pi = __shfl_xor(idx[m], j);
        bool isLower = ((lane & j) == 0);
        double lo = isLower ? key[m] : pk;
        double hi = isLower ? pk : key[m];
        if ((lo > hi) == up){ key[m] = pk; idx[m] = pi; }
      }
    }
  }
  #pragma unroll
  for (int m = 0; m < 4; m++){ int i = m*1024 + tid; ks_[i] = key[m]; is_[i] = idx[m]; }
  __syncthreads();

  for (int k = 128; k <= NSEQ; k <<= 1){
    for (int j = k >> 1; j >= 64; j >>= 1){
      for (int i = tid; i < NSEQ; i += 1024){
        int ixj = i ^ j;
        if (ixj > i){
          double a = ks_[i], b = ks_[ixj];
          bool up = ((i & k) == 0);
          if ((a > b) == up){
            ks_[i] = b; ks_[ixj] = a;
            int tmp = is_[i]; is_[i] = is_[ixj]; is_[ixj] = tmp;
          }
        }
      }
      __syncthreads();
    }
    #pragma unroll
    for (int m = 0; m < 4; m++){ int i = m*1024 + tid; key[m] = ks_[i]; idx[m] = is_[i]; }
    #pragma unroll
    for (int j = 32; j > 0; j >>= 1){
      #pragma unroll
      for (int m = 0; m < 4; m++){
        int i = m*1024 + tid;
        bool up = ((i & k) == 0);
        double pk = __shfl_xor(key[m], j);
        int    pi = __shfl_xor(idx[m], j);
        bool isLower = ((lane & j) == 0);
        double lo = isLower ? key[m] : pk;
        double hi = isLower ? pk : key[m];
        if ((lo > hi) == up){ key[m] = pk; idx[m] = pi; }
      }
    }
    #pragma unroll
    for (int m = 0; m < 4; m++){ int i = m*1024 + tid; ks_[i] = key[m]; is_[i] = idx[m]; }
    __syncthreads();
  }
  for (int i = tid; i < NSEQ; i += 1024){ int t = is_[i]; pos[i] = t; rev[t] = i; }
}

// ---------------- R17: Performer features — tiled loop-swap (proven) ----------------
__global__ __launch_bounds__(256) void k_feat(const float* __restrict__ query, const float* __restrict__ key,
                                              const float* __restrict__ projW, char* __restrict__ ws){
  int tid = threadIdx.x, lane = tid & 63, wid = tid >> 6;
  __shared__ __align__(16) float s_x[4][16][EDIM];   // 16 KB
  float* qp  = (float*)(ws+OFF_QP);
  float* qls = (float*)(ws+OFF_QLS);
  float* kp  = (float*)(ws+OFF_KP);
  const float* w0p = projW + (size_t)lane*EDIM;        // W[lane][e]
  const float* w1p = projW + (size_t)(64+lane)*EDIM;   // W[64+lane][e]

  // ================= q half =================
  {
    float ss[16];
    #pragma unroll
    for (int it = 0; it < 16; it++){
      int p = blockIdx.x*64 + wid*16 + it;
      int bh = p >> 12, t = p & (NSEQ-1), bo = bh >> 3, hh = bh & 7;
      float xv = query[((size_t)bo*NSEQ + t)*DD + hh*EDIM + lane] * SQRT_TEMP;
      s_x[wid][it][lane] = xv;
      float s = xv*xv;
      for (int o = 32; o; o >>= 1) s += __shfl_xor(s, o);
      ss[it] = s;
    }
    float a0[16], a1[16];
    #pragma unroll
    for (int it = 0; it < 16; it++){ a0[it] = 0.f; a1[it] = 0.f; }
    #pragma unroll 1
    for (int e4 = 0; e4 < 16; e4++){
      float4 w0 = *(const float4*)(w0p + e4*4);
      float4 w1 = *(const float4*)(w1p + e4*4);
      #pragma unroll
      for (int it = 0; it < 16; it++){
        float4 sx = *(const float4*)&s_x[wid][it][e4*4];
        a0[it] = fmaf(sx.x, w0.x, a0[it]);
        a1[it] = fmaf(sx.x, w1.x, a1[it]);
        a0[it] = fmaf(sx.y, w0.y, a0[it]);
        a1[it] = fmaf(sx.y, w1.y, a1[it]);
        a0[it] = fmaf(sx.z, w0.z, a0[it]);
        a1[it] = fmaf(sx.z, w1.z, a1[it]);
        a0[it] = fmaf(sx.w, w0.w, a0[it]);
        a1[it] = fmaf(sx.w, w1.w, a1[it]);
      }
    }
    #pragma unroll
    for (int it = 0; it < 16; it++){
      int p = blockIdx.x*64 + wid*16 + it;
      float c = 0.5f*ss[it] + HALF_LOG_M;
      float lp0 = a0[it] - c, lp1 = a1[it] - c;
      float mx = fmaxf(lp0, lp1);
      for (int o = 32; o; o >>= 1) mx = fmaxf(mx, __shfl_xor(mx, o));
      size_t base = (size_t)p*MDIM;
      qp[base + lane]      = expf(lp0 - mx);
      qp[base + 64 + lane] = expf(lp1 - mx);
      if (!lane) qls[p] = mx;
    }
  }

  // ================= k half =================
  int bh0 = (blockIdx.x*64) >> 12;
  float bmax = -INFINITY;
  {
    float ss[16];
    #pragma unroll
    for (int it = 0; it < 16; it++){
      int p = blockIdx.x*64 + wid*16 + it;
      int bh = p >> 12, t = p & (NSEQ-1), bo = bh >> 3, hh = bh & 7;
      float xv = key[((size_t)bo*NSEQ + t)*DD + hh*EDIM + lane] * SQRT_TEMP;
      s_x[wid][it][lane] = xv;
      float s = xv*xv;
      for (int o = 32; o; o >>= 1) s += __shfl_xor(s, o);
      ss[it] = s;
    }
    float a0[16], a1[16];
    #pragma unroll
    for (int it = 0; it < 16; it++){ a0[it] = 0.f; a1[it] = 0.f; }
    #pragma unroll 1
    for (int e4 = 0; e4 < 16; e4++){
      float4 w0 = *(const float4*)(w0p + e4*4);
      float4 w1 = *(const float4*)(w1p + e4*4);
      #pragma unroll
      for (int it = 0; it < 16; it++){
        float4 sx = *(const float4*)&s_x[wid][it][e4*4];
        a0[it] = fmaf(sx.x, w0.x, a0[it]);
        a1[it] = fmaf(sx.x, w1.x, a1[it]);
        a0[it] = fmaf(sx.y, w0.y, a0[it]);
        a1[it] = fmaf(sx.y, w1.y, a1[it]);
        a0[it] = fmaf(sx.z, w0.z, a0[it]);
        a1[it] = fmaf(sx.z, w1.z, a1[it]);
        a0[it] = fmaf(sx.w, w0.w, a0[it]);
        a1[it] = fmaf(sx.w, w1.w, a1[it]);
      }
    }
    #pragma unroll
    for (int it = 0; it < 16; it++){
      int p = blockIdx.x*64 + wid*16 + it;
      float c = 0.5f*ss[it] + HALF_LOG_M;
      float lp0 = a0[it] - c, lp1 = a1[it] - c;
      size_t base = (size_t)p*MDIM;
      kp[base + lane]      = lp0;
      kp[base + 64 + lane] = lp1;
      float mx = fmaxf(lp0, lp1);
      for (int o = 32; o; o >>= 1) mx = fmaxf(mx, __shfl_xor(mx, o));
      bmax = fmaxf(bmax, mx);
    }
  }
  __shared__ float wm[4];
  if (!lane) wm[wid] = bmax;
  __syncthreads();
  if (!tid){
    float m = fmaxf(fmaxf(wm[0], wm[1]), fmaxf(wm[2], wm[3]));
    atomicMax((unsigned*)(ws+OFF_KLS) + bh0, encF(m));
  }
}

// ---------------- kv split-k stage 1 — R18: also writes kpb bf16 mirror ----------------
// The staged skp tile already holds expf(lp - stab); casting it to bf16 here
// is the SAME cast k_cvt's kp half performed -> identical bytes in kpb, and
// k_cvt no longer needs to re-read KP (67 MB) or redo the exp.
__global__ __launch_bounds__(256, 4) void k_kv(const float* __restrict__ value, char* __restrict__ ws){
  int b = blockIdx.x >> 4;          // bh
  int chunk = blockIdx.x & 15;      // 16 chunks x 256 seq positions
  int bo = b >> 3, hh = b & 7;
  const float* kp = (const float*)(ws+OFF_KP) + (size_t)b*NSEQ*MDIM;  // raw lp
  bf16_t* kpb = (bf16_t*)(ws+OFF_KPB) + (size_t)b*NSEQ*MDIM;
  float stab = decF(((const unsigned*)(ws+OFF_KLS))[b]);
  __shared__ float skp[32][MDIM];   // 16 KB
  __shared__ float sv [32][EDIM];   //  8 KB
  int tid = threadIdx.x;
  int d = tid & 63, mg = tid >> 6;
  int m0 = mg*32;
  float acc[32];
  #pragma unroll
  for (int i = 0; i < 32; i++) acc[i] = 0.f;
  float ksacc = 0.f;
  #pragma unroll 1
  for (int s0 = chunk*256; s0 < chunk*256 + 256; s0 += 32){
    __syncthreads();
    {
      const float4* src = (const float4*)(kp + (size_t)s0*MDIM);
      #pragma unroll
      for (int l = tid; l < 32*MDIM/4; l += 256){
        float4 x = src[l];
        x.x = expf(x.x - stab); x.y = expf(x.y - stab);
        x.z = expf(x.z - stab); x.w = expf(x.w - stab);
        ((float4*)skp)[l] = x;
        *(bf16x4*)(kpb + (size_t)(s0 + (l >> 5))*MDIM + ((l & 31) << 2)) =
            (bf16x4){(bf16_t)x.x,(bf16_t)x.y,(bf16_t)x.z,(bf16_t)x.w};
      }
    }
    #pragma unroll
    for (int l = tid; l < 32*EDIM/4; l += 256){
      int r = l >> 4, c4 = (l & 15) << 2;
      *(float4*)&sv[r][c4] = *(const float4*)(value + ((size_t)bo*NSEQ + s0 + r)*DD + hh*EDIM + c4);
    }
    __syncthreads();
    #pragma unroll 1
    for (int ss = 0; ss < 32; ss += 2){
      float vv0 = sv[ss+0][d];
      float vv1 = sv[ss+1][d];
      #pragma unroll
      for (int mq = 0; mq < 8; mq++){
        float4 k0 = *(const float4*)&skp[ss+0][m0 + mq*4];
        float4 k1 = *(const float4*)&skp[ss+1][m0 + mq*4];
        acc[mq*4+0] = fmaf(k0.x, vv0, acc[mq*4+0]);
        acc[mq*4+1] = fmaf(k0.y, vv0, acc[mq*4+1]);
        acc[mq*4+2] = fmaf(k0.z, vv0, acc[mq*4+2]);
        acc[mq*4+3] = fmaf(k0.w, vv0, acc[mq*4+3]);
        acc[mq*4+0] = fmaf(k1.x, vv1, acc[mq*4+0]);
        acc[mq*4+1] = fmaf(k1.y, vv1, acc[mq*4+1]);
        acc[mq*4+2] = fmaf(k1.z, vv1, acc[mq*4+2]);
        acc[mq*4+3] = fmaf(k1.w, vv1, acc[mq*4+3]);
      }
    }
    if (tid < 128){
      #pragma unroll
      for (int ss = 0; ss < 32; ss++) ksacc += skp[ss][tid];
    }
  }
  float* pkv = (float*)(ws+OFF_PKV) + ((size_t)(b*NCHUNK + chunk)*MDIM + m0)*EDIM + d;
  #pragma unroll
  for (int mi = 0; mi < 32; mi++) pkv[mi*EDIM] = acc[mi];
  if (tid < 128)
    ((float*)(ws+OFF_PKS))[(b*NCHUNK + chunk)*MDIM + tid] = ksacc;
}

// ---------------- kv split-k stage 2 ----------------
__global__ __launch_bounds__(256) void k_kvred(char* __restrict__ ws){
  int blk = blockIdx.x;
  if (blk < 1024){                              // kv: 32*128*64 = 262144 elements
    int idx = blk*256 + threadIdx.x;
    int b = idx >> 13, rem = idx & 8191;
    const float* pkv = (const float*)(ws+OFF_PKV);
    float s = 0.f;
    #pragma unroll
    for (int c = 0; c < NCHUNK; c++) s += pkv[(((size_t)b*NCHUNK + c) << 13) + rem];
    ((float*)(ws+OFF_KV))[idx] = s;
  } else {                                      // ksum: 32*128 = 4096 elements
    int j = (blk - 1024)*256 + threadIdx.x;
    const float* pks = (const float*)(ws+OFF_PKS);
    int b = j >> 7, m = j & 127;
    float s = 0.f;
    #pragma unroll
    for (int c = 0; c < NCHUNK; c++) s += pks[(b*NCHUNK + c)*MDIM + m];
    ((float*)(ws+OFF_KSUM))[j] = s;
  }
}

// ---------------- R18: v-only bf16 mirror (kp half moved into k_kv) ----------------
__global__ __launch_bounds__(256) void k_cvt(const float* __restrict__ value, char* __restrict__ ws){
  bf16_t* vb = (bf16_t*)(ws+OFF_VB);
  size_t idx = (size_t)blockIdx.x*256 + threadIdx.x;   // 2.1M float4
  int e4 = (int)(idx & 15) << 2;
  int t  = (int)((idx >> 4) & 4095);
  int b  = (int)(idx >> 16);
  int bo = b >> 3, hh = b & 7;
  float4 x = *(const float4*)(value + ((size_t)bo*NSEQ + t)*DD + hh*EDIM + e4);
  *(bf16x4*)(vb + ((size_t)b*NSEQ + t)*EDIM + e4) =
      (bf16x4){(bf16_t)x.x,(bf16_t)x.y,(bf16_t)x.z,(bf16_t)x.w};
}

// ---------------- bucketed exact correction — MFMA (R13 version, unchanged) ----------------
__global__ __launch_bounds__(256, 2) void k_bucket(const float* __restrict__ query,
                                                   const float* __restrict__ key,
                                                   char* __restrict__ ws){
  __shared__ __align__(16) bf16_t s_kT[128*72];    // Kt[j][e],  stride 72  (18.4 KB)
  __shared__ __align__(16) bf16_t s_kp[128*136];   // KPt[j][m], stride 136 (34.8 KB) — reused as dots[i][j]
  __shared__ __align__(16) bf16_t s_v [64*136];    // Vt[d][j],  stride 136 (17.4 KB)
  __shared__ int   s_tq[128], s_tk[128], s_qb[128], s_kb[128];
  __shared__ float s_pls[128];

  int blk = blockIdx.x;
  int h = blk >> 10;           // hash
  int b = (blk >> 5) & 31;     // bh
  int n = blk & 31;            // bucket
  int tid = threadIdx.x, lane = tid & 63, wid = tid >> 6;
  int col = lane & 31, half = lane >> 5;
  int bo = b >> 3, hh = b & 7;

  const int* kpos  = (const int*)(ws+OFF_KPOS) + ((size_t)h*BH + b)*NSEQ + n*BSZC;
  const int* qpos  = (const int*)(ws+OFF_QPOS) + ((size_t)h*BH + b)*NSEQ + n*BSZC;
  const int* qrev0 = (const int*)(ws+OFF_QREV) + (size_t)b*NSEQ;
  const int* qrev1 = (const int*)(ws+OFF_QREV) + ((size_t)BH + b)*NSEQ;
  const int* krev0 = (const int*)(ws+OFF_KREV) + (size_t)b*NSEQ;
  const int* krev1 = (const int*)(ws+OFF_KREV) + ((size_t)BH + b)*NSEQ;
  const float* qp_g = (const float*)(ws+OFF_QP) + (size_t)b*NSEQ*MDIM;
  const bf16_t* kpb_g = (const bf16_t*)(ws+OFF_KPB) + (size_t)b*NSEQ*MDIM;
  const bf16_t* vb_g  = (const bf16_t*)(ws+OFF_VB)  + (size_t)b*NSEQ*EDIM;
  const float* qls  = (const float*)(ws+OFF_QLS) + (size_t)b*NSEQ;
  float klsb = decF(((const unsigned*)(ws+OFF_KLS))[b]);

  if (tid < 128){
    int t = qpos[tid];
    s_tq[tid]  = t;
    s_pls[tid] = qls[t] + klsb;
    s_qb[tid]  = (qrev0[t] >> 7) | ((qrev1[t] >> 7) << 16);
  } else {
    int j = tid - 128;
    int t = kpos[j];
    s_tk[j] = t;
    s_kb[j] = (krev0[t] >> 7) | ((krev1[t] >> 7) << 16);
  }
  __syncthreads();

  // ---- prefetch per-lane A-fragments (raw) — latency hides under staging ----
  int mrow = wid*32 + col;
  int tq_m = s_tq[mrow];
  const float* qr  = query + ((size_t)bo*NSEQ + tq_m)*DD + hh*EDIM + half*8;
  const float* qpr = qp_g + (size_t)tq_m*MDIM + half*8;
  float4 aqf[8];
  #pragma unroll
  for (int kb = 0; kb < 4; kb++){
    aqf[2*kb]   = *(const float4*)(qr + kb*16);
    aqf[2*kb+1] = *(const float4*)(qr + kb*16 + 4);
  }
  float4 aqpf[16];
  #pragma unroll
  for (int kb = 0; kb < 8; kb++){
    aqpf[2*kb]   = *(const float4*)(qpr + kb*16);
    aqpf[2*kb+1] = *(const float4*)(qpr + kb*16 + 4);
  }

  for (int l = tid; l < 128*16; l += 256){            // K: 128 rows x 64 e (f32)
    int j = l >> 4, e4 = (l & 15) << 2;
    int t = s_tk[j];
    float4 x = *(const float4*)(key + ((size_t)bo*NSEQ + t)*DD + hh*EDIM + e4);
    bf16x4 y = {(bf16_t)x.x, (bf16_t)x.y, (bf16_t)x.z, (bf16_t)x.w};
    *(bf16x4*)&s_kT[j*72 + e4] = y;
  }
  for (int l = tid; l < 128*16; l += 256){            // KP: 128 rows x 128 m (bf16x8)
    int j = l >> 4, m8 = (l & 15) << 3;
    int t = s_tk[j];
    *(bf16x8*)&s_kp[j*136 + m8] = *(const bf16x8*)(kpb_g + (size_t)t*MDIM + m8);
  }
  for (int l = tid; l < 128*8; l += 256){             // V (bf16x8) -> Vt[d][j]
    int j = l >> 3, d8 = (l & 7) << 3;
    int t = s_tk[j];
    bf16x8 vv = *(const bf16x8*)(vb_g + (size_t)t*EDIM + d8);
    #pragma unroll
    for (int i = 0; i < 8; i++) s_v[(d8+i)*136 + j] = vv[i];
  }
  __syncthreads();

  float* o_g   = (float*)(ws+OFF_O)    + ((size_t)h*BH + b)*NSEQ*EDIM;
  float* lse_g = (float*)(ws+OFF_LSE)  + ((size_t)h*BH + b)*NSEQ;
  float* dsm_g = (float*)(ws+OFF_DSUM) + ((size_t)h*BH + b)*NSEQ;

  // ---- matmul 1: inner = Q @ K^T ----
  bf16x8 aq[4];
  #pragma unroll
  for (int kb = 0; kb < 4; kb++){
    float4 x0 = aqf[2*kb], x1 = aqf[2*kb+1];
    aq[kb] = (bf16x8){(bf16_t)x0.x,(bf16_t)x0.y,(bf16_t)x0.z,(bf16_t)x0.w,
                      (bf16_t)x1.x,(bf16_t)x1.y,(bf16_t)x1.z,(bf16_t)x1.w};
  }
  f32x16_t ain[4] = {Z16, Z16, Z16, Z16};
  #pragma unroll
  for (int jt = 0; jt < 4; jt++){
    #pragma unroll
    for (int kb = 0; kb < 4; kb++){
      bf16x8 bk = *(const bf16x8*)&s_kT[(jt*32 + col)*72 + kb*16 + half*8];
      ain[jt] = __builtin_amdgcn_mfma_f32_32x32x16_bf16(aq[kb], bk, ain[jt], 0, 0, 0);
    }
  }

  // ---- matmul 2: dots_prime = QP @ KP^T ----
  bf16x8 aqp[8];
  #pragma unroll
  for (int kb = 0; kb < 8; kb++){
    float4 x0 = aqpf[2*kb], x1 = aqpf[2*kb+1];
    aqp[kb] = (bf16x8){(bf16_t)x0.x,(bf16_t)x0.y,(bf16_t)x0.z,(bf16_t)x0.w,
                       (bf16_t)x1.x,(bf16_t)x1.y,(bf16_t)x1.z,(bf16_t)x1.w};
  }
  f32x16_t apr[4] = {Z16, Z16, Z16, Z16};
  #pragma unroll
  for (int jt = 0; jt < 4; jt++){
    #pragma unroll
    for (int kb = 0; kb < 8; kb++){
      bf16x8 bk = *(const bf16x8*)&s_kp[(jt*32 + col)*136 + kb*16 + half*8];
      apr[jt] = __builtin_amdgcn_mfma_f32_32x32x16_bf16(aqp[kb], bk, apr[jt], 0, 0, 0);
    }
  }
  __syncthreads();   // everyone done reading s_kp — safe to overwrite with dots

  // ---- softmax-correction ----
  float pls_r[16]; int qb_r[16];
  #pragma unroll
  for (int i = 0; i < 16; i++){
    int r = wid*32 + (i & 3) + 8*(i >> 2) + 4*half;
    pls_r[i] = s_pls[r];
    qb_r[i]  = s_qb[r];
  }
  float mx[16];
  #pragma unroll
  for (int i = 0; i < 16; i++) mx[i] = -INFINITY;
  #pragma unroll
  for (int jt = 0; jt < 4; jt++){
    int kbp = s_kb[jt*32 + col];
    int kb0 = kbp & 0xffff, kb1 = kbp >> 16;
    #pragma unroll
    for (int i = 0; i < 16; i++){
      int dup2 = ((qb_r[i] & 0xffff) == kb0) & ((qb_r[i] >> 16) == kb1);
      float in = ain[jt][i]*0.125f - (dup2 ? LN2F : 0.0f);
      float dp = dup2 ? apr[jt][i]*0.5f : apr[jt][i];
      ain[jt][i] = in; apr[jt][i] = dp;
      mx[i] = fmaxf(mx[i], in);
    }
  }
  #pragma unroll
  for (int i = 0; i < 16; i++){
    #pragma unroll
    for (int o = 16; o; o >>= 1) mx[i] = fmaxf(mx[i], __shfl_xor(mx[i], o));
  }
  float L[16], eps[16], dsum[16];
  #pragma unroll
  for (int i = 0; i < 16; i++){
    L[i] = fmaxf(mx[i], pls_r[i]);
    eps[i] = expf(pls_r[i] - L[i]);
    dsum[i] = 0.f;
  }
  #pragma unroll
  for (int jt = 0; jt < 4; jt++){
    #pragma unroll
    for (int i = 0; i < 16; i++){
      float d = expf(ain[jt][i] - L[i]) - apr[jt][i]*eps[i];
      dsum[i] += d;
      int r = wid*32 + (i & 3) + 8*(i >> 2) + 4*half;
      s_kp[r*136 + jt*32 + col] = (bf16_t)d;        // dots[i][j] (A-layout for matmul 3)
    }
  }
  #pragma unroll
  for (int i = 0; i < 16; i++){
    #pragma unroll
    for (int o = 16; o; o >>= 1) dsum[i] += __shfl_xor(dsum[i], o);
  }
  __syncthreads();

  // ---- matmul 3: so = dots @ V ----
  f32x16_t ao[2] = {Z16, Z16};
  #pragma unroll
  for (int kb = 0; kb < 8; kb++){
    bf16x8 ad = *(const bf16x8*)&s_kp[mrow*136 + kb*16 + half*8];
    #pragma unroll
    for (int dt = 0; dt < 2; dt++){
      bf16x8 bv = *(const bf16x8*)&s_v[(dt*32 + col)*136 + kb*16 + half*8];
      ao[dt] = __builtin_amdgcn_mfma_f32_32x32x16_bf16(ad, bv, ao[dt], 0, 0, 0);
    }
  }

  // ---- epilogue: scatter to unsorted positions ----
  #pragma unroll
  for (int i = 0; i < 16; i++){
    int r = wid*32 + (i & 3) + 8*(i >> 2) + 4*half;
    int t = s_tq[r];
    o_g[(size_t)t*EDIM + col]      = ao[0][i];
    o_g[(size_t)t*EDIM + 32 + col] = ao[1][i];
    if (col == 0){ lse_g[t] = L[i]; dsm_g[t] = dsum[i]; }
  }
}

// ---------------- combine — R18 loop-swap (R17 medicine for the qkv loop) ----------------
// Old inner loop: 2 LDS b32 reads per fma x 128 m x 16 pos/thread = 4096 LDS
// instr/thread (~100-125 us LDS-pipe-bound). New: kv transposed to s_kvT[e][132]
// (16B-aligned rows), qp tile staged per-wave [16][128]; m4 outer reads kv once
// as float4, 16 broadcast float4 qp reads inner -> 544 LDS instr/thread.
// fma order per position: m ascending (m4 asc, x->w) == old order -> bit-identical.
__global__ __launch_bounds__(256) void k_combine(char* __restrict__ ws){
  int b = blockIdx.x >> 6;
  int chunk = blockIdx.x & 63;
  int tid = threadIdx.x, lane = tid & 63, wid = tid >> 6;
  __shared__ __align__(16) float s_kvT[EDIM*132];   // [e][m], stride 132 (33.8 KB)
  __shared__ float s_ks[MDIM];
  __shared__ __align__(16) float s_qp[4][16][MDIM]; // 32 KB
  const float* kv = (const float*)(ws+OFF_KV) + (size_t)b*MDIM*EDIM;
  for (int l = tid; l < MDIM*EDIM; l += 256){
    int m = l >> 6, e = l & 63;
    s_kvT[e*132 + m] = kv[l];
  }
  if (tid < MDIM) s_ks[tid] = ((const float*)(ws+OFF_KSUM))[b*MDIM + tid];
  const float* qp_g  = (const float*)(ws+OFF_QP) + (size_t)b*NSEQ*MDIM;
  int t0 = chunk*64 + wid*16;
  for (int l = lane; l < 16*32; l += 64){
    int it = l >> 5, m4 = l & 31;
    *(float4*)&s_qp[wid][it][m4*4] = *(const float4*)(qp_g + (size_t)(t0+it)*MDIM + m4*4);
  }
  __syncthreads();
  const float* qls   = (const float*)(ws+OFF_QLS) + (size_t)b*NSEQ;
  const float* lse_g = (const float*)(ws+OFF_LSE);
  const float* dsm_g = (const float*)(ws+OFF_DSUM);
  const float* o_g   = (const float*)(ws+OFF_O);
  float* outn = (float*)(ws+OFF_OUTN);
  float klsb = decF(((const unsigned*)(ws+OFF_KLS))[b]);
  int bo = b >> 3, hh = b & 7;

  float qkv[16];
  #pragma unroll
  for (int it = 0; it < 16; it++) qkv[it] = 0.f;
  #pragma unroll 1
  for (int m4 = 0; m4 < 32; m4++){
    float4 kv4 = *(const float4*)&s_kvT[lane*132 + m4*4];
    #pragma unroll
    for (int it = 0; it < 16; it++){
      float4 q4 = *(const float4*)&s_qp[wid][it][m4*4];
      qkv[it] = fmaf(q4.x, kv4.x, qkv[it]);
      qkv[it] = fmaf(q4.y, kv4.y, qkv[it]);
      qkv[it] = fmaf(q4.z, kv4.z, qkv[it]);
      qkv[it] = fmaf(q4.w, kv4.w, qkv[it]);
    }
  }

  #pragma unroll 1
  for (int it = 0; it < 16; it++){
    int t = t0 + it;
    float qp0 = s_qp[wid][it][lane];
    float qp1 = s_qp[wid][it][64 + lane];
    float qk1 = qp0*s_ks[lane] + qp1*s_ks[64 + lane];
    for (int o = 32; o; o >>= 1) qk1 += __shfl_xor(qk1, o);
    size_t pidx = (size_t)b*NSEQ + t;
    float l0 = lse_g[pidx], l1 = lse_g[(size_t)BH*NSEQ + pidx];
    float mx = fmaxf(l0, l1);
    float nls = mx + logf(expf(l0 - mx) + expf(l1 - mx));
    float p0 = expf(l0 - nls), p1 = expf(l1 - nls);
    float ps = expf(qls[t] + klsb - nls);
    float o0 = o_g[pidx*EDIM + lane];
    float o1 = o_g[((size_t)BH*NSEQ + pidx)*EDIM + lane];
    float ds0 = dsm_g[pidx], ds1 = dsm_g[(size_t)BH*NSEQ + pidx];
    float outv = o0*p0 + o1*p1 + qkv[it]*ps;
    float nrm  = ds0*p0 + ds1*p1 + qk1*ps;
    outn[((size_t)bo*NSEQ + t)*DD + hh*EDIM + lane] = outv / fmaxf(nrm, 1e-6f);
  }
}

// ---------------- final projection (R11 version) ----------------
__global__ __launch_bounds__(256) void k_final(const float* __restrict__ outW, const float* __restrict__ outB,
                                               const char* __restrict__ ws, float* __restrict__ out){
  __shared__ float WT[DD*65];      // [d][e], padded
  __shared__ float s_x[4][DD];
  int tid = threadIdx.x, lane = tid & 63, wid = tid >> 6;
  for (int l = tid; l < EDIM*DD; l += 256){
    int e = l >> 9, d = l & 511;
    WT[d*65 + e] = outW[l];
  }
  __syncthreads();
  const float* outn = (const float*)(ws+OFF_OUTN);
  for (int it = 0; it < 16; it++){
    int p = blockIdx.x*64 + wid*16 + it;
    const float* x = outn + (size_t)p*DD;
    #pragma unroll
    for (int c = 0; c < 8; c++) s_x[wid][c*64 + lane] = x[c*64 + lane];
    float acc = 0.f;
    for (int d = 0; d < DD; d++) acc = fmaf(s_x[wid][d], WT[d*65 + lane], acc);
    out[(size_t)p*EDIM + lane] = acc + outB[lane];
  }
}

extern "C" void kernel_launch(void* const* d_in, const int* in_sizes, int n_in,
                              void* d_out, int out_size, void* d_ws, size_t ws_size,
                              hipStream_t stream) {
  const float* query = (const float*)d_in[0];
  const float* key   = (const float*)d_in[1];
  const float* value = (const float*)d_in[2];
  const float* projW = (const float*)d_in[3];
  const float* alpha = (const float*)d_in[4];
  const float* beta  = (const float*)d_in[5];
  const float* outW  = (const float*)d_in[6];
  const float* outB  = (const float*)d_in[7];
  char* ws = (char*)d_ws;
  float* out = (float*)d_out;

  k_init <<<1,    256, 0, stream>>>(ws);
  k_sumsq<<<512,  256, 0, stream>>>(query, key, alpha, ws);
  k_hash <<<512,  256, 0, stream>>>(alpha, beta, ws);
  k_sort <<<128, 1024, 0, stream>>>(ws);
  k_feat <<<2048, 256, 0, stream>>>(query, key, projW, ws);
  k_kv   <<<512,  256, 0, stream>>>(value, ws);
  k_kvred<<<1040, 256, 0, stream>>>(ws);
  k_cvt  <<<8192, 256, 0, stream>>>(value, ws);
  k_bucket<<<2048,256, 0, stream>>>(query, key, ws);
  k_combine<<<2048,256,0, stream>>>(ws);
  k_final<<<256,  256, 0, stream>>>(outW, outB, ws, out);
}